// Round 1
// baseline (988.781 us; speedup 1.0000x reference)
//
#include <hip/hip_runtime.h>
#include <math.h>

#define NB 2
#define NL 1024
#define ND 768
#define NH 12
#define DH 64

// ---------------------------------------------------------------------------
// Kernel A: QKV projection.  out[b,h,l,d] = hs[b,l,:] @ W[:, h*64+d] + bias
// 64x64 output tile per block, 256 threads, 4x4 per thread, KT=16.
// ---------------------------------------------------------------------------
__global__ __launch_bounds__(256) void qkv_kernel(
    const float* __restrict__ hs,
    const float* __restrict__ Wq, const float* __restrict__ bq,
    const float* __restrict__ Wk, const float* __restrict__ bk,
    const float* __restrict__ Wv, const float* __restrict__ bv,
    float* __restrict__ qbuf, float* __restrict__ kbuf, float* __restrict__ vbuf)
{
    __shared__ float sA[16][68];   // [k][m] transposed, pad 68 -> conflict-free b128 reads
    __shared__ float sB[16][64];   // [k][n]

    const int m0  = blockIdx.x * 64;
    const int y   = blockIdx.y;          // 0..35
    const int mat = y / NH;
    const int h   = y % NH;
    const int n0  = h * DH;

    const float* W; const float* bias; float* outb;
    if (mat == 0)      { W = Wq; bias = bq; outb = qbuf; }
    else if (mat == 1) { W = Wk; bias = bk; outb = kbuf; }
    else               { W = Wv; bias = bv; outb = vbuf; }

    const int t  = threadIdx.x;
    const int tr = t >> 4;    // 0..15 (row group)
    const int tc = t & 15;    // 0..15 (col group)

    float acc[4][4];
    #pragma unroll
    for (int r = 0; r < 4; ++r)
        #pragma unroll
        for (int c = 0; c < 4; ++c) acc[r][c] = 0.f;

    for (int k0 = 0; k0 < ND; k0 += 16) {
        #pragma unroll
        for (int r = 0; r < 4; ++r) {
            int e = t + 256 * r;            // 1024 elements
            int m = e >> 4, c = e & 15;
            sA[c][m] = hs[(m0 + m) * ND + k0 + c];
        }
        #pragma unroll
        for (int r = 0; r < 4; ++r) {
            int e = t + 256 * r;
            int n = e & 63, kk = e >> 6;
            sB[kk][n] = W[(k0 + kk) * ND + n0 + n];
        }
        __syncthreads();
        #pragma unroll
        for (int kk = 0; kk < 16; ++kk) {
            float a[4], b[4];
            *(float4*)a = *(const float4*)&sA[kk][tr * 4];
            *(float4*)b = *(const float4*)&sB[kk][tc * 4];
            #pragma unroll
            for (int r = 0; r < 4; ++r)
                #pragma unroll
                for (int c = 0; c < 4; ++c)
                    acc[r][c] += a[r] * b[c];
        }
        __syncthreads();
    }

    float bvv[4];
    *(float4*)bvv = *(const float4*)&bias[n0 + tc * 4];
    #pragma unroll
    for (int rr = 0; rr < 4; ++rr) {
        int m = m0 + tr * 4 + rr;
        int bb = m >> 10, l = m & 1023;
        float res[4];
        #pragma unroll
        for (int c = 0; c < 4; ++c) res[c] = acc[rr][c] + bvv[c];
        *(float4*)&outb[((bb * NH + h) * NL + l) * DH + tc * 4] = *(float4*)res;
    }
}

// ---------------------------------------------------------------------------
// Kernel B: qw[i,b,h,l,e] = sum_d q[b,h,l,d] * ssan_w[i,h,d,e]
// one 64x64 @ 64x64 GEMM tile per block.
// ---------------------------------------------------------------------------
__global__ __launch_bounds__(256) void qw_kernel(
    const float* __restrict__ qbuf, const float* __restrict__ ssan_w,
    float* __restrict__ qwbuf)
{
    __shared__ float sQt[64][68];  // [d][l]
    __shared__ float sW[64][64];   // [d][e]

    const int l0 = blockIdx.x * 64;
    const int z  = blockIdx.y;      // 0..119
    const int ii = z / 24;
    const int bh = z % 24;          // b*12 + h
    const float* qsrc = qbuf + (bh * NL + l0) * DH;
    const float* wsrc = ssan_w + (ii * NH + (bh % NH)) * DH * DH;

    const int t = threadIdx.x;
    #pragma unroll
    for (int r = 0; r < 16; ++r) {
        int e = t + 256 * r;
        sQt[e & 63][e >> 6] = qsrc[e];
        ((float*)sW)[e] = wsrc[e];
    }
    __syncthreads();

    const int tr = t >> 4, tc = t & 15;
    float acc[4][4];
    #pragma unroll
    for (int r = 0; r < 4; ++r)
        #pragma unroll
        for (int c = 0; c < 4; ++c) acc[r][c] = 0.f;

    #pragma unroll 8
    for (int kk = 0; kk < 64; ++kk) {
        float a[4], b[4];
        *(float4*)a = *(const float4*)&sQt[kk][tr * 4];
        *(float4*)b = *(const float4*)&sW[kk][tc * 4];
        #pragma unroll
        for (int r = 0; r < 4; ++r)
            #pragma unroll
            for (int c = 0; c < 4; ++c)
                acc[r][c] += a[r] * b[c];
    }

    float* dst = qwbuf + ((ii * 24 + bh) * NL + l0) * DH;
    #pragma unroll
    for (int rr = 0; rr < 4; ++rr) {
        *(float4*)&dst[(tr * 4 + rr) * DH + tc * 4] = *(float4*)&acc[rr][0];
    }
}

// ---------------------------------------------------------------------------
// Kernel C: fused flash attention with relative-position and SSAN bias terms.
// Block = (q-tile of 32 rows) x (b,h).  K-tiles of 64, online softmax.
// score(l,r) = (q.k + (q+k).E[l-r]) / 8 + mask[b,r]
//            + sum_i (qw_i.k + ab[i]) * struct_i[b,l,r]
// ---------------------------------------------------------------------------
__global__ __launch_bounds__(256) void attn_kernel(
    const float* __restrict__ qbuf, const float* __restrict__ kbuf,
    const float* __restrict__ vbuf, const float* __restrict__ qwbuf,
    const float* __restrict__ mask, const float* __restrict__ struct_m,
    const float* __restrict__ dist_emb, const float* __restrict__ abs_bias,
    float* __restrict__ out)
{
    __shared__ float sQ[32 * 68];
    __shared__ float sQW[5][32 * 68];
    __shared__ float sK[64 * 68];
    __shared__ float sV[64 * 68];
    __shared__ float sE[96 * 68];   // rows 0..94 used: E[base + (i-j+63)]
    __shared__ float sS[32 * 68];

    const int l0 = blockIdx.x * 32;
    const int bh = blockIdx.y;              // b*12 + h
    const int bb = bh / NH, h = bh % NH;
    const int t  = threadIdx.x;
    const int i  = t >> 3;                  // query row within tile, 0..31
    const int jb = t & 7;                   // 8 threads per row (same wave)
    const int db = jb * 8;                  // d-slice for PV phase

    // ---- stage Q and QW tiles (fixed for the whole block) ----
    {
        const float* qsrc = qbuf + (bh * NL + l0) * DH;
        #pragma unroll
        for (int r = 0; r < 8; ++r) {
            int e = t + 256 * r;            // 2048 elements
            sQ[(e >> 6) * 68 + (e & 63)] = qsrc[e];
        }
        #pragma unroll
        for (int ii = 0; ii < 5; ++ii) {
            const float* qwsrc = qwbuf + ((ii * 24 + bh) * NL + l0) * DH;
            #pragma unroll
            for (int r = 0; r < 8; ++r) {
                int e = t + 256 * r;
                sQW[ii][(e >> 6) * 68 + (e & 63)] = qwsrc[e];
            }
        }
    }

    float ab[5];
    #pragma unroll
    for (int ii = 0; ii < 5; ++ii) ab[ii] = abs_bias[ii * NH + h];

    float m_cur = -INFINITY, l_cur = 0.f;
    float o[8];
    #pragma unroll
    for (int c = 0; c < 8; ++c) o[c] = 0.f;

    for (int kt = 0; kt < 16; ++kt) {
        const int r0 = kt * 64;
        __syncthreads();   // previous PV readers done before restaging
        {
            const float* ksrc = kbuf + (bh * NL + r0) * DH;
            const float* vsrc = vbuf + (bh * NL + r0) * DH;
            #pragma unroll
            for (int r = 0; r < 16; ++r) {
                int e = t + 256 * r;        // 4096 elements
                int ro = e >> 6, d = e & 63;
                sK[ro * 68 + d] = ksrc[e];
                sV[ro * 68 + d] = vsrc[e];
            }
            // E band: rows (l0-r0+960) .. +94 — contiguous in memory
            const float* esrc = dist_emb + (l0 - r0 + 960) * DH;
            for (int e = t; e < 95 * 64; e += 256)
                sE[(e >> 6) * 68 + (e & 63)] = esrc[e];
        }
        __syncthreads();

        // ---- prefetch struct & mask for this tile (hides HBM latency) ----
        float stv[5][8], mv[8];
        {
            const int srow = (l0 + i) * NL + r0 + jb;
            #pragma unroll
            for (int jj = 0; jj < 8; ++jj) {
                mv[jj] = mask[bb * NL + r0 + jb + 8 * jj];
                #pragma unroll
                for (int ii = 0; ii < 5; ++ii)
                    stv[ii][jj] = struct_m[(ii * NB + bb) * (NL * NL) + srow + 8 * jj];
            }
        }

        // ---- score accumulation ----
        float accA[8], accW[5][8];
        #pragma unroll
        for (int jj = 0; jj < 8; ++jj) {
            accA[jj] = 0.f;
            #pragma unroll
            for (int ii = 0; ii < 5; ++ii) accW[ii][jj] = 0.f;
        }

        #pragma unroll 4
        for (int d4 = 0; d4 < 16; ++d4) {
            const int doff = d4 * 4;
            float qv[4], wv[5][4];
            *(float4*)qv = *(const float4*)&sQ[i * 68 + doff];
            #pragma unroll
            for (int ii = 0; ii < 5; ++ii)
                *(float4*)wv[ii] = *(const float4*)&sQW[ii][i * 68 + doff];
            #pragma unroll
            for (int jj = 0; jj < 8; ++jj) {
                const int j = jb + 8 * jj;
                float kv[4], ev[4];
                *(float4*)kv = *(const float4*)&sK[j * 68 + doff];
                *(float4*)ev = *(const float4*)&sE[(i - j + 63) * 68 + doff];
                #pragma unroll
                for (int d = 0; d < 4; ++d)
                    accA[jj] += qv[d] * kv[d] + (qv[d] + kv[d]) * ev[d];
                #pragma unroll
                for (int ii = 0; ii < 5; ++ii)
                    #pragma unroll
                    for (int d = 0; d < 4; ++d)
                        accW[ii][jj] += wv[ii][d] * kv[d];
            }
        }

        // ---- finalize scores, online softmax ----
        float sv[8];
        float smax = -INFINITY;
        #pragma unroll
        for (int jj = 0; jj < 8; ++jj) {
            float s = accA[jj] * 0.125f + mv[jj];
            #pragma unroll
            for (int ii = 0; ii < 5; ++ii)
                s += (accW[ii][jj] + ab[ii]) * stv[ii][jj];
            sv[jj] = s;
            smax = fmaxf(smax, s);
        }
        #pragma unroll
        for (int off = 4; off > 0; off >>= 1)
            smax = fmaxf(smax, __shfl_xor(smax, off, 8));
        const float m_new = fmaxf(m_cur, smax);
        const float alpha = __expf(m_cur - m_new);   // -inf -> 0 on first tile
        float rsum = 0.f;
        #pragma unroll
        for (int jj = 0; jj < 8; ++jj) {
            float p = __expf(sv[jj] - m_new);
            sS[i * 68 + jb + 8 * jj] = p;
            rsum += p;
        }
        #pragma unroll
        for (int off = 4; off > 0; off >>= 1)
            rsum += __shfl_xor(rsum, off, 8);
        l_cur = l_cur * alpha + rsum;
        m_cur = m_new;

        __syncthreads();   // sS published (also orders vs restage next iter)

        // ---- PV accumulate: o[i][db..db+8] += p[i][j] * V[j][db..] ----
        #pragma unroll
        for (int c = 0; c < 8; ++c) o[c] *= alpha;
        #pragma unroll 8
        for (int j = 0; j < 64; ++j) {
            float p = sS[i * 68 + j];
            float vv[8];
            *(float4*)vv       = *(const float4*)&sV[j * 68 + db];
            *(float4*)(vv + 4) = *(const float4*)&sV[j * 68 + db + 4];
            #pragma unroll
            for (int c = 0; c < 8; ++c) o[c] += p * vv[c];
        }
    }

    const float inv = 1.f / l_cur;
    float res[8];
    #pragma unroll
    for (int c = 0; c < 8; ++c) res[c] = o[c] * inv;
    float* dst = out + (bb * NL + l0 + i) * ND + h * DH + db;
    *(float4*)dst       = *(float4*)res;
    *(float4*)(dst + 4) = *(float4*)(res + 4);
}

// ---------------------------------------------------------------------------
extern "C" void kernel_launch(void* const* d_in, const int* in_sizes, int n_in,
                              void* d_out, int out_size, void* d_ws, size_t ws_size,
                              hipStream_t stream) {
    const float* hs   = (const float*)d_in[0];
    const float* mask = (const float*)d_in[1];
    const float* stm  = (const float*)d_in[2];
    const float* Wq   = (const float*)d_in[3];
    const float* bq   = (const float*)d_in[4];
    const float* Wk   = (const float*)d_in[5];
    const float* bk   = (const float*)d_in[6];
    const float* Wv   = (const float*)d_in[7];
    const float* bv   = (const float*)d_in[8];
    const float* de   = (const float*)d_in[9];
    const float* sw   = (const float*)d_in[10];
    const float* abb  = (const float*)d_in[11];
    float* outp = (float*)d_out;

    const int NQKV = NB * NH * NL * DH;      // 1,572,864 floats
    float* qbuf  = (float*)d_ws;
    float* kbuf  = qbuf + NQKV;
    float* vbuf  = kbuf + NQKV;
    float* qwbuf = vbuf + NQKV;              // 5 * NQKV floats

    qkv_kernel<<<dim3(32, 36), 256, 0, stream>>>(hs, Wq, bq, Wk, bk, Wv, bv,
                                                 qbuf, kbuf, vbuf);
    qw_kernel<<<dim3(16, 120), 256, 0, stream>>>(qbuf, sw, qwbuf);
    attn_kernel<<<dim3(32, 24), 256, 0, stream>>>(qbuf, kbuf, vbuf, qwbuf,
                                                  mask, stm, de, abb, outp);
}

// Round 2
// 391.909 us; speedup vs baseline: 2.5230x; 2.5230x over previous
//
#include <hip/hip_runtime.h>
#include <math.h>

#define NB 2
#define NL 1024
#define ND 768
#define NH 12
#define DH 64

typedef unsigned short ushort_t;
typedef float f32x4 __attribute__((ext_vector_type(4)));
typedef short bf16x8 __attribute__((ext_vector_type(8)));

__device__ __forceinline__ ushort_t bf16_rne(float x) {
    unsigned int u = __float_as_uint(x);
    unsigned int r = (u + 0x7FFFu + ((u >> 16) & 1u)) >> 16;
    return (ushort_t)r;
}
__device__ __forceinline__ float bf16_f(ushort_t h) {
    return __uint_as_float(((unsigned int)h) << 16);
}
__device__ __forceinline__ bf16x8 ldfrag(const ushort_t* p) {
    return *(const bf16x8*)p;
}
#define MFMA(a, b, c) __builtin_amdgcn_mfma_f32_16x16x32_bf16((a), (b), (c), 0, 0, 0)

// ---------------------------------------------------------------------------
// Kernel A: QKV projection (fp32 GEMM, unchanged math).  Epilogue writes:
//   mat 0: qbuf fp32 [bh][l][d]  +  qhi/qlo bf16 [bh][l][d]
//   mat 1: khi/klo bf16 [bh][l][d]
//   mat 2: vt bf16 [bh][d][l]   (transposed for PV B-fragments)
// ---------------------------------------------------------------------------
__global__ __launch_bounds__(256) void qkv_kernel(
    const float* __restrict__ hs,
    const float* __restrict__ Wq, const float* __restrict__ bq,
    const float* __restrict__ Wk, const float* __restrict__ bk,
    const float* __restrict__ Wv, const float* __restrict__ bv,
    float* __restrict__ qbuf,
    ushort_t* __restrict__ qhi, ushort_t* __restrict__ qlo,
    ushort_t* __restrict__ khi, ushort_t* __restrict__ klo,
    ushort_t* __restrict__ vt)
{
    __shared__ float sA[16][68];
    __shared__ float sB[16][64];

    const int m0  = blockIdx.x * 64;
    const int y   = blockIdx.y;          // 0..35
    const int mat = y / NH;
    const int h   = y % NH;
    const int n0  = h * DH;

    const float* W; const float* bias;
    if (mat == 0)      { W = Wq; bias = bq; }
    else if (mat == 1) { W = Wk; bias = bk; }
    else               { W = Wv; bias = bv; }

    const int t  = threadIdx.x;
    const int tr = t >> 4;
    const int tc = t & 15;

    float acc[4][4];
    #pragma unroll
    for (int r = 0; r < 4; ++r)
        #pragma unroll
        for (int c = 0; c < 4; ++c) acc[r][c] = 0.f;

    for (int k0 = 0; k0 < ND; k0 += 16) {
        #pragma unroll
        for (int r = 0; r < 4; ++r) {
            int e = t + 256 * r;
            int m = e >> 4, c = e & 15;
            sA[c][m] = hs[(m0 + m) * ND + k0 + c];
        }
        #pragma unroll
        for (int r = 0; r < 4; ++r) {
            int e = t + 256 * r;
            int n = e & 63, kk = e >> 6;
            sB[kk][n] = W[(k0 + kk) * ND + n0 + n];
        }
        __syncthreads();
        #pragma unroll
        for (int kk = 0; kk < 16; ++kk) {
            float a[4], b[4];
            *(float4*)a = *(const float4*)&sA[kk][tr * 4];
            *(float4*)b = *(const float4*)&sB[kk][tc * 4];
            #pragma unroll
            for (int r = 0; r < 4; ++r)
                #pragma unroll
                for (int c = 0; c < 4; ++c)
                    acc[r][c] += a[r] * b[c];
        }
        __syncthreads();
    }

    float bvv[4];
    *(float4*)bvv = *(const float4*)&bias[n0 + tc * 4];
    #pragma unroll
    for (int rr = 0; rr < 4; ++rr) {
        int m = m0 + tr * 4 + rr;
        int bb = m >> 10, l = m & 1023;
        const int bh = bb * NH + h;
        #pragma unroll
        for (int c = 0; c < 4; ++c) {
            float x = acc[rr][c] + bvv[c];
            int d = tc * 4 + c;
            if (mat == 0) {
                qbuf[(bh * NL + l) * DH + d] = x;
                ushort_t hi = bf16_rne(x);
                qhi[(bh * NL + l) * DH + d] = hi;
                qlo[(bh * NL + l) * DH + d] = bf16_rne(x - bf16_f(hi));
            } else if (mat == 1) {
                ushort_t hi = bf16_rne(x);
                khi[(bh * NL + l) * DH + d] = hi;
                klo[(bh * NL + l) * DH + d] = bf16_rne(x - bf16_f(hi));
            } else {
                vt[(bh * DH + d) * NL + l] = bf16_rne(x);
            }
        }
    }
}

// ---------------------------------------------------------------------------
// Kernel B: qw[i,bh,l,e] = q[bh,l,:] @ ssan_w[i,h]  (fp32 GEMM, bf16 output)
// ---------------------------------------------------------------------------
__global__ __launch_bounds__(256) void qw_kernel(
    const float* __restrict__ qbuf, const float* __restrict__ ssan_w,
    ushort_t* __restrict__ qwb)
{
    __shared__ float sQt[64][68];
    __shared__ float sW[64][64];

    const int l0 = blockIdx.x * 64;
    const int z  = blockIdx.y;      // 0..119
    const int ii = z / 24;
    const int bh = z % 24;
    const float* qsrc = qbuf + (bh * NL + l0) * DH;
    const float* wsrc = ssan_w + (ii * NH + (bh % NH)) * DH * DH;

    const int t = threadIdx.x;
    #pragma unroll
    for (int r = 0; r < 16; ++r) {
        int e = t + 256 * r;
        sQt[e & 63][e >> 6] = qsrc[e];
        ((float*)sW)[e] = wsrc[e];
    }
    __syncthreads();

    const int tr = t >> 4, tc = t & 15;
    float acc[4][4];
    #pragma unroll
    for (int r = 0; r < 4; ++r)
        #pragma unroll
        for (int c = 0; c < 4; ++c) acc[r][c] = 0.f;

    #pragma unroll 8
    for (int kk = 0; kk < 64; ++kk) {
        float a[4], b[4];
        *(float4*)a = *(const float4*)&sQt[kk][tr * 4];
        *(float4*)b = *(const float4*)&sW[kk][tc * 4];
        #pragma unroll
        for (int r = 0; r < 4; ++r)
            #pragma unroll
            for (int c = 0; c < 4; ++c)
                acc[r][c] += a[r] * b[c];
    }

    ushort_t* dst = qwb + ((ii * 24 + bh) * NL + l0) * DH;
    #pragma unroll
    for (int rr = 0; rr < 4; ++rr)
        #pragma unroll
        for (int c = 0; c < 4; ++c)
            dst[(tr * 4 + rr) * DH + tc * 4 + c] = bf16_rne(acc[rr][c]);
}

// ---------------------------------------------------------------------------
// Kernel C: MFMA flash attention.  512 threads (8 waves), q-tile 64, k-tile 64.
// Wave w owns S-subtiles (m = w>>1, n in {2*(w&1), 2*(w&1)+1}).
// Products: QK (q hi/lo split, 3 MFMA) + 5 bilinears (qw plain x k hi/lo, 2 each).
// Pos terms via band GEMMs QEb = Q@Eband^T, KEb = K@Eband^T, diagonal gather.
// ---------------------------------------------------------------------------
__global__ __launch_bounds__(512, 2) void attn_kernel(
    const ushort_t* __restrict__ qhi_g, const ushort_t* __restrict__ qlo_g,
    const ushort_t* __restrict__ khi_g, const ushort_t* __restrict__ klo_g,
    const ushort_t* __restrict__ vt_g,  const ushort_t* __restrict__ qwb_g,
    const float* __restrict__ mask, const float* __restrict__ struct_m,
    const float* __restrict__ dist_emb, const float* __restrict__ abs_bias,
    float* __restrict__ out)
{
    __shared__ ushort_t sQhi[64 * 72], sQlo[64 * 72];
    __shared__ ushort_t sQW[5 * 64 * 72];
    __shared__ ushort_t sKhi[64 * 72], sKlo[64 * 72];
    __shared__ ushort_t sVt[64 * 72];
    __shared__ ushort_t sEb[128 * 72];           // overlaid by sS (float[64*68])
    __shared__ ushort_t sQE[64 * 136], sKE[64 * 136];
    __shared__ ushort_t sP[64 * 72];
    __shared__ float sAlpha[64], sL[64];
    float* sS = (float*)sEb;

    const int l0 = blockIdx.x * 64;
    const int bh = blockIdx.y;
    const int bb = bh / NH, h = bh % NH;
    const int t  = threadIdx.x;
    const int lane  = t & 63;
    const int w     = t >> 6;       // wave 0..7
    const int quad  = lane >> 4;
    const int l15   = lane & 15;
    const int msub  = w >> 1;       // 0..3
    const int npair = w & 1;        // 0..1

    // staging coords: each thread moves 8 contiguous ushorts
    const int srow = t >> 3;            // 0..63
    const int scol = (t & 7) * 8;       // 0..56

    // ---- stage Q-side tiles (once per block) ----
    {
        const int qb = (bh * NL + l0) * DH;
        *(uint4*)&sQhi[srow * 72 + scol] = *(const uint4*)&qhi_g[qb + srow * 64 + scol];
        *(uint4*)&sQlo[srow * 72 + scol] = *(const uint4*)&qlo_g[qb + srow * 64 + scol];
        #pragma unroll
        for (int p = 0; p < 5; ++p) {
            const int wb = ((p * 24 + bh) * NL + l0) * DH;
            *(uint4*)&sQW[p * 4608 + srow * 72 + scol] = *(const uint4*)&qwb_g[wb + srow * 64 + scol];
        }
    }

    float ab[5];
    #pragma unroll
    for (int p = 0; p < 5; ++p) ab[p] = abs_bias[p * NH + h];

    // softmax state (row-mapped threads: row = t>>3, jb = t&7)
    const int sm_i  = t >> 3;
    const int sm_jb = t & 7;
    float m_cur = -INFINITY, l_cur = 0.f;

    // PV accumulators (C-layout): rows 16*msub + 4*quad + r, cols 32*npair+16*n+l15
    f32x4 O[2];
    O[0] = (f32x4){0.f, 0.f, 0.f, 0.f};
    O[1] = (f32x4){0.f, 0.f, 0.f, 0.f};

    for (int kt = 0; kt < 16; ++kt) {
        const int r0 = kt * 64;
        __syncthreads();   // previous-iteration readers done (also covers Q staging)

        // ---- Phase A: stage K/V/E ----
        {
            const int kb = (bh * NL + r0) * DH;
            *(uint4*)&sKhi[srow * 72 + scol] = *(const uint4*)&khi_g[kb + srow * 64 + scol];
            *(uint4*)&sKlo[srow * 72 + scol] = *(const uint4*)&klo_g[kb + srow * 64 + scol];
            *(uint4*)&sVt[srow * 72 + scol] =
                *(const uint4*)&vt_g[bh * DH * NL + srow * NL + r0 + scol];
            const int ebase = l0 - r0 + 960;
            for (int e = t * 8; e < 127 * 64; e += 4096) {
                int er = e >> 6, ec = e & 63;
                float4 f0 = *(const float4*)&dist_emb[(ebase + er) * 64 + ec];
                float4 f1 = *(const float4*)&dist_emb[(ebase + er) * 64 + ec + 4];
                ushort_t u[8];
                u[0] = bf16_rne(f0.x); u[1] = bf16_rne(f0.y);
                u[2] = bf16_rne(f0.z); u[3] = bf16_rne(f0.w);
                u[4] = bf16_rne(f1.x); u[5] = bf16_rne(f1.y);
                u[6] = bf16_rne(f1.z); u[7] = bf16_rne(f1.w);
                *(uint4*)&sEb[er * 72 + ec] = *(uint4*)u;
            }
        }
        __syncthreads();

        // ---- Phase B: pos band GEMMs ----
        {
            const int arow = 16 * msub + l15;
            bf16x8 aq0 = ldfrag(&sQhi[arow * 72 + quad * 8]);
            bf16x8 aq1 = ldfrag(&sQhi[arow * 72 + 32 + quad * 8]);
            bf16x8 ak0 = ldfrag(&sKhi[arow * 72 + quad * 8]);
            bf16x8 ak1 = ldfrag(&sKhi[arow * 72 + 32 + quad * 8]);
            #pragma unroll
            for (int nn = 0; nn < 4; ++nn) {
                const int nb = npair * 4 + nn;           // diag subtile 0..7
                const int brow = 16 * nb + l15;
                bf16x8 e0 = ldfrag(&sEb[brow * 72 + quad * 8]);
                bf16x8 e1 = ldfrag(&sEb[brow * 72 + 32 + quad * 8]);
                f32x4 cq = {0.f, 0.f, 0.f, 0.f};
                cq = MFMA(aq0, e0, cq);
                cq = MFMA(aq1, e1, cq);
                f32x4 ck = {0.f, 0.f, 0.f, 0.f};
                ck = MFMA(ak0, e0, ck);
                ck = MFMA(ak1, e1, ck);
                #pragma unroll
                for (int r = 0; r < 4; ++r) {
                    sQE[(16 * msub + 4 * quad + r) * 136 + 16 * nb + l15] = bf16_rne(cq[r]);
                    sKE[(16 * msub + 4 * quad + r) * 136 + 16 * nb + l15] = bf16_rne(ck[r]);
                }
            }
        }
        __syncthreads();

        // ---- Phase C: main score MFMAs + epilogue into sS ----
        {
            // prefetch struct & mask
            float stv[5][2][4];
            float mv[2];
            #pragma unroll
            for (int n = 0; n < 2; ++n) {
                const int j = 32 * npair + 16 * n + l15;
                mv[n] = mask[bb * NL + r0 + j];
                #pragma unroll
                for (int r = 0; r < 4; ++r) {
                    const int i = 16 * msub + 4 * quad + r;
                    #pragma unroll
                    for (int p = 0; p < 5; ++p)
                        stv[p][n][r] =
                            struct_m[((p * NB + bb) * NL + l0 + i) * NL + r0 + j];
                }
            }

            f32x4 acc[2][6];
            #pragma unroll
            for (int n = 0; n < 2; ++n)
                #pragma unroll
                for (int p = 0; p < 6; ++p)
                    acc[n][p] = (f32x4){0.f, 0.f, 0.f, 0.f};

            const int arow = 16 * msub + l15;
            #pragma unroll
            for (int K = 0; K < 2; ++K) {
                const int koff = K * 32 + quad * 8;
                bf16x8 kh[2], kl[2];
                #pragma unroll
                for (int n = 0; n < 2; ++n) {
                    const int krow = 32 * npair + 16 * n + l15;
                    kh[n] = ldfrag(&sKhi[krow * 72 + koff]);
                    kl[n] = ldfrag(&sKlo[krow * 72 + koff]);
                }
                bf16x8 ah = ldfrag(&sQhi[arow * 72 + koff]);
                bf16x8 al = ldfrag(&sQlo[arow * 72 + koff]);
                #pragma unroll
                for (int n = 0; n < 2; ++n) {
                    acc[n][0] = MFMA(ah, kh[n], acc[n][0]);
                    acc[n][0] = MFMA(al, kh[n], acc[n][0]);
                    acc[n][0] = MFMA(ah, kl[n], acc[n][0]);
                }
                #pragma unroll
                for (int p = 0; p < 5; ++p) {
                    bf16x8 aw = ldfrag(&sQW[p * 4608 + arow * 72 + koff]);
                    #pragma unroll
                    for (int n = 0; n < 2; ++n) {
                        acc[n][1 + p] = MFMA(aw, kh[n], acc[n][1 + p]);
                        acc[n][1 + p] = MFMA(aw, kl[n], acc[n][1 + p]);
                    }
                }
            }

            #pragma unroll
            for (int n = 0; n < 2; ++n) {
                const int j = 32 * npair + 16 * n + l15;
                #pragma unroll
                for (int r = 0; r < 4; ++r) {
                    const int i = 16 * msub + 4 * quad + r;
                    const int tt = i - j + 63;
                    float posq = bf16_f(sQE[i * 136 + tt]);
                    float posk = bf16_f(sKE[j * 136 + tt]);
                    float s = (acc[n][0][r] + posq + posk) * 0.125f + mv[n];
                    #pragma unroll
                    for (int p = 0; p < 5; ++p)
                        s += (acc[n][1 + p][r] + ab[p]) * stv[p][n][r];
                    sS[i * 68 + j] = s;
                }
            }
        }
        __syncthreads();

        // ---- Phase D: online softmax (row-mapped) ----
        {
            float sv[8];
            float smax = -INFINITY;
            #pragma unroll
            for (int k = 0; k < 8; ++k) {
                sv[k] = sS[sm_i * 68 + sm_jb + 8 * k];
                smax = fmaxf(smax, sv[k]);
            }
            #pragma unroll
            for (int off = 4; off > 0; off >>= 1)
                smax = fmaxf(smax, __shfl_xor(smax, off, 8));
            const float m_new = fmaxf(m_cur, smax);
            const float alpha = __expf(m_cur - m_new);
            float rsum = 0.f;
            #pragma unroll
            for (int k = 0; k < 8; ++k) {
                float p = __expf(sv[k] - m_new);
                sP[sm_i * 72 + sm_jb + 8 * k] = bf16_rne(p);
                rsum += p;
            }
            #pragma unroll
            for (int off = 4; off > 0; off >>= 1)
                rsum += __shfl_xor(rsum, off, 8);
            l_cur = l_cur * alpha + rsum;
            m_cur = m_new;
            if (sm_jb == 0) { sAlpha[sm_i] = alpha; sL[sm_i] = l_cur; }
        }
        __syncthreads();

        // ---- Phase E: PV MFMA with alpha rescale ----
        {
            float a4[4];
            #pragma unroll
            for (int r = 0; r < 4; ++r) a4[r] = sAlpha[16 * msub + 4 * quad + r];
            #pragma unroll
            for (int n = 0; n < 2; ++n)
                #pragma unroll
                for (int r = 0; r < 4; ++r) O[n][r] *= a4[r];
            const int prow = 16 * msub + l15;
            #pragma unroll
            for (int K = 0; K < 2; ++K) {
                const int koff = K * 32 + quad * 8;
                bf16x8 pf = ldfrag(&sP[prow * 72 + koff]);
                #pragma unroll
                for (int n = 0; n < 2; ++n) {
                    bf16x8 vf = ldfrag(&sVt[(32 * npair + 16 * n + l15) * 72 + koff]);
                    O[n] = MFMA(pf, vf, O[n]);
                }
            }
        }
    }

    // ---- final output ----
    float linv[4];
    #pragma unroll
    for (int r = 0; r < 4; ++r) linv[r] = 1.0f / sL[16 * msub + 4 * quad + r];
    #pragma unroll
    for (int n = 0; n < 2; ++n) {
        const int dh = 32 * npair + 16 * n + l15;
        #pragma unroll
        for (int r = 0; r < 4; ++r) {
            const int i = 16 * msub + 4 * quad + r;
            out[(bb * NL + l0 + i) * ND + h * DH + dh] = O[n][r] * linv[r];
        }
    }
}

// ---------------------------------------------------------------------------
extern "C" void kernel_launch(void* const* d_in, const int* in_sizes, int n_in,
                              void* d_out, int out_size, void* d_ws, size_t ws_size,
                              hipStream_t stream) {
    const float* hs   = (const float*)d_in[0];
    const float* mask = (const float*)d_in[1];
    const float* stm  = (const float*)d_in[2];
    const float* Wq   = (const float*)d_in[3];
    const float* bq   = (const float*)d_in[4];
    const float* Wk   = (const float*)d_in[5];
    const float* bk   = (const float*)d_in[6];
    const float* Wv   = (const float*)d_in[7];
    const float* bv   = (const float*)d_in[8];
    const float* de   = (const float*)d_in[9];
    const float* sw   = (const float*)d_in[10];
    const float* abb  = (const float*)d_in[11];
    float* outp = (float*)d_out;

    const size_t NQKV = (size_t)NB * NH * NL * DH;       // 1,572,864
    char* ws = (char*)d_ws;
    float*    qbuf = (float*)ws;                          ws += NQKV * 4;
    ushort_t* qhi  = (ushort_t*)ws;                       ws += NQKV * 2;
    ushort_t* qlo  = (ushort_t*)ws;                       ws += NQKV * 2;
    ushort_t* khi  = (ushort_t*)ws;                       ws += NQKV * 2;
    ushort_t* klo  = (ushort_t*)ws;                       ws += NQKV * 2;
    ushort_t* vt   = (ushort_t*)ws;                       ws += NQKV * 2;
    ushort_t* qwb  = (ushort_t*)ws;                       ws += 5 * NQKV * 2;

    qkv_kernel<<<dim3(32, 36), 256, 0, stream>>>(hs, Wq, bq, Wk, bk, Wv, bv,
                                                 qbuf, qhi, qlo, khi, klo, vt);
    qw_kernel<<<dim3(16, 120), 256, 0, stream>>>(qbuf, sw, qwb);
    attn_kernel<<<dim3(16, 24), 512, 0, stream>>>(qhi, qlo, khi, klo, vt, qwb,
                                                  mask, stm, de, abb, outp);
}

// Round 3
// 346.051 us; speedup vs baseline: 2.8573x; 1.1325x over previous
//
#include <hip/hip_runtime.h>
#include <math.h>

#define NB 2
#define NL 1024
#define ND 768
#define NH 12
#define DH 64

typedef _Float16 f16;
typedef _Float16 f16x4 __attribute__((ext_vector_type(4)));
typedef _Float16 f16x8 __attribute__((ext_vector_type(8)));
typedef float f32x4 __attribute__((ext_vector_type(4)));

#define MFMA16(a, b, c) __builtin_amdgcn_mfma_f32_16x16x32_f16((a), (b), (c), 0, 0, 0)

// ---------------------------------------------------------------------------
// Kernel A: QKV projection, fp32 math.  Outputs:
//   mat0: qbuf fp32 [bh][l][d] (for qw) + qf f16 [bh][l][d]
//   mat1: kf f16 [bh][l][d]
//   mat2: vt f16 [bh][d][l]  (transposed via LDS bounce, coalesced stores)
// ---------------------------------------------------------------------------
__global__ __launch_bounds__(256) void qkv_kernel(
    const float* __restrict__ hs,
    const float* __restrict__ Wq, const float* __restrict__ bq,
    const float* __restrict__ Wk, const float* __restrict__ bk,
    const float* __restrict__ Wv, const float* __restrict__ bv,
    float* __restrict__ qbuf, f16* __restrict__ qf,
    f16* __restrict__ kf, f16* __restrict__ vt)
{
    __shared__ float sA[16][68];
    __shared__ float sB[16][64];
    __shared__ float sT[64 * 69];   // mat2 transpose bounce

    const int m0  = blockIdx.x * 64;
    const int y   = blockIdx.y;          // 0..35
    const int mat = y / NH;
    const int h   = y % NH;
    const int n0  = h * DH;

    const float* W; const float* bias;
    if (mat == 0)      { W = Wq; bias = bq; }
    else if (mat == 1) { W = Wk; bias = bk; }
    else               { W = Wv; bias = bv; }

    const int t  = threadIdx.x;
    const int tr = t >> 4;
    const int tc = t & 15;

    float acc[4][4];
    #pragma unroll
    for (int r = 0; r < 4; ++r)
        #pragma unroll
        for (int c = 0; c < 4; ++c) acc[r][c] = 0.f;

    for (int k0 = 0; k0 < ND; k0 += 16) {
        #pragma unroll
        for (int r = 0; r < 4; ++r) {
            int e = t + 256 * r;
            int m = e >> 4, c = e & 15;
            sA[c][m] = hs[(m0 + m) * ND + k0 + c];
        }
        #pragma unroll
        for (int r = 0; r < 4; ++r) {
            int e = t + 256 * r;
            int n = e & 63, kk = e >> 6;
            sB[kk][n] = W[(k0 + kk) * ND + n0 + n];
        }
        __syncthreads();
        #pragma unroll
        for (int kk = 0; kk < 16; ++kk) {
            float a[4], b[4];
            *(float4*)a = *(const float4*)&sA[kk][tr * 4];
            *(float4*)b = *(const float4*)&sB[kk][tc * 4];
            #pragma unroll
            for (int r = 0; r < 4; ++r)
                #pragma unroll
                for (int c = 0; c < 4; ++c)
                    acc[r][c] += a[r] * b[c];
        }
        __syncthreads();
    }

    float bvv[4];
    *(float4*)bvv = *(const float4*)&bias[n0 + tc * 4];
    const int bb = m0 >> 10;           // uniform per block (1024 % 64 == 0)
    const int lbase = m0 & 1023;
    const int bh = bb * NH + h;

    if (mat == 2) {
        #pragma unroll
        for (int rr = 0; rr < 4; ++rr)
            #pragma unroll
            for (int c = 0; c < 4; ++c)
                sT[(4 * tr + rr) * 69 + 4 * tc + c] = acc[rr][c] + bvv[c];
        __syncthreads();
        const int td  = t >> 2;          // 0..63 (d)
        const int tl0 = (t & 3) * 16;    // l chunk
        f16 tmp[16];
        #pragma unroll
        for (int jj = 0; jj < 16; ++jj)
            tmp[jj] = (f16)sT[(tl0 + jj) * 69 + td];
        f16* dst = vt + ((size_t)bh * DH + td) * NL + lbase + tl0;
        *(f16x8*)dst       = *(f16x8*)&tmp[0];
        *(f16x8*)(dst + 8) = *(f16x8*)&tmp[8];
    } else {
        #pragma unroll
        for (int rr = 0; rr < 4; ++rr) {
            const int l = lbase + 4 * tr + rr;
            float res[4];
            f16x4 hres;
            #pragma unroll
            for (int c = 0; c < 4; ++c) {
                res[c] = acc[rr][c] + bvv[c];
                hres[c] = (f16)res[c];
            }
            if (mat == 0) {
                *(float4*)&qbuf[((size_t)bh * NL + l) * DH + tc * 4] = *(float4*)res;
                *(f16x4*)&qf[((size_t)bh * NL + l) * DH + tc * 4] = hres;
            } else {
                *(f16x4*)&kf[((size_t)bh * NL + l) * DH + tc * 4] = hres;
            }
        }
    }
}

// ---------------------------------------------------------------------------
// Kernel B: qw[p,bh,l,e] = q[bh,l,:] @ ssan_w[p,h]  (fp32 math, f16 out)
// ---------------------------------------------------------------------------
__global__ __launch_bounds__(256) void qw_kernel(
    const float* __restrict__ qbuf, const float* __restrict__ ssan_w,
    f16* __restrict__ qwf)
{
    __shared__ float sQt[64][68];
    __shared__ float sW[64][64];

    const int l0 = blockIdx.x * 64;
    const int z  = blockIdx.y;      // 0..119
    const int ii = z / 24;
    const int bh = z % 24;
    const float* qsrc = qbuf + ((size_t)bh * NL + l0) * DH;
    const float* wsrc = ssan_w + ((size_t)ii * NH + (bh % NH)) * DH * DH;

    const int t = threadIdx.x;
    #pragma unroll
    for (int r = 0; r < 16; ++r) {
        int e = t + 256 * r;
        sQt[e & 63][e >> 6] = qsrc[e];
        ((float*)sW)[e] = wsrc[e];
    }
    __syncthreads();

    const int tr = t >> 4, tc = t & 15;
    float acc[4][4];
    #pragma unroll
    for (int r = 0; r < 4; ++r)
        #pragma unroll
        for (int c = 0; c < 4; ++c) acc[r][c] = 0.f;

    #pragma unroll 8
    for (int kk = 0; kk < 64; ++kk) {
        float a[4], b[4];
        *(float4*)a = *(const float4*)&sQt[kk][tr * 4];
        *(float4*)b = *(const float4*)&sW[kk][tc * 4];
        #pragma unroll
        for (int r = 0; r < 4; ++r)
            #pragma unroll
            for (int c = 0; c < 4; ++c)
                acc[r][c] += a[r] * b[c];
    }

    f16* dst = qwf + ((size_t)(ii * 24 + bh) * NL + l0) * DH;
    #pragma unroll
    for (int rr = 0; rr < 4; ++rr) {
        f16x4 hv;
        #pragma unroll
        for (int c = 0; c < 4; ++c) hv[c] = (f16)acc[rr][c];
        *(f16x4*)&dst[(tr * 4 + rr) * DH + tc * 4] = hv;
    }
}

// ---------------------------------------------------------------------------
// Kernel P: posb[bh][l][r] = (q[bh,l] + k[bh,r]) . dist_emb[l-r+1023]   (f16)
// One (bh, l-tile 64, r-tile 64) per block, 256 threads (4 waves), f16 MFMA
// band GEMMs QE = Q@E^T, KE = K@E^T (tt = local diag index), diagonal gather.
// ---------------------------------------------------------------------------
__global__ __launch_bounds__(256, 2) void pos_kernel(
    const f16* __restrict__ qf, const f16* __restrict__ kf,
    const float* __restrict__ dist_emb, f16* __restrict__ posb)
{
    __shared__ f16 sQ[64 * 72], sK2[64 * 72];
    __shared__ f16 sE[128 * 72];
    __shared__ f16 sQE[64 * 140], sKE[64 * 140];

    const int l0 = blockIdx.x * 64;
    const int r0 = blockIdx.y * 64;
    const int bh = blockIdx.z;
    const int t  = threadIdx.x;
    const int lane = t & 63;
    const int w    = t >> 6;       // 0..3
    const int quad = lane >> 4;
    const int l15  = lane & 15;

    // ---- stage ----
    {
        const int row = t >> 3, col = (t & 7) * 8;
        const f16* qs = qf + ((size_t)bh * NL + l0) * DH;
        const f16* ks = kf + ((size_t)bh * NL + r0) * DH;
        *(f16x8*)&sQ[row * 72 + col]        = *(const f16x8*)&qs[row * 64 + col];
        *(f16x8*)&sQ[(row + 32) * 72 + col] = *(const f16x8*)&qs[(row + 32) * 64 + col];
        *(f16x8*)&sK2[row * 72 + col]        = *(const f16x8*)&ks[row * 64 + col];
        *(f16x8*)&sK2[(row + 32) * 72 + col] = *(const f16x8*)&ks[(row + 32) * 64 + col];
        const int ebase = l0 - r0 + 960;
        #pragma unroll
        for (int p = 0; p < 4; ++p) {
            const int er = row + 32 * p;
            if (er < 127) {
                const float* es = dist_emb + (size_t)(ebase + er) * DH + col;
                float4 a = *(const float4*)es;
                float4 b = *(const float4*)(es + 4);
                f16x8 hv;
                hv[0] = (f16)a.x; hv[1] = (f16)a.y; hv[2] = (f16)a.z; hv[3] = (f16)a.w;
                hv[4] = (f16)b.x; hv[5] = (f16)b.y; hv[6] = (f16)b.z; hv[7] = (f16)b.w;
                *(f16x8*)&sE[er * 72 + col] = hv;
            }
        }
    }
    __syncthreads();

    // ---- band GEMMs ----
    {
        const int arow = (16 * w + l15) * 72 + quad * 8;
        f16x8 aq0 = *(f16x8*)&sQ[arow];
        f16x8 aq1 = *(f16x8*)&sQ[arow + 32];
        f16x8 ak0 = *(f16x8*)&sK2[arow];
        f16x8 ak1 = *(f16x8*)&sK2[arow + 32];
        #pragma unroll
        for (int n = 0; n < 8; ++n) {
            const int brow = (16 * n + l15) * 72 + quad * 8;
            f16x8 e0 = *(f16x8*)&sE[brow];
            f16x8 e1 = *(f16x8*)&sE[brow + 32];
            f32x4 cq = {0.f, 0.f, 0.f, 0.f};
            cq = MFMA16(aq0, e0, cq);
            cq = MFMA16(aq1, e1, cq);
            f32x4 ck = {0.f, 0.f, 0.f, 0.f};
            ck = MFMA16(ak0, e0, ck);
            ck = MFMA16(ak1, e1, ck);
            #pragma unroll
            for (int r = 0; r < 4; ++r) {
                sQE[(16 * w + 4 * quad + r) * 140 + 16 * n + l15] = (f16)cq[r];
                sKE[(16 * w + 4 * quad + r) * 140 + 16 * n + l15] = (f16)ck[r];
            }
        }
    }
    __syncthreads();

    // ---- diagonal gather + coalesced write ----
    {
        const int i  = t >> 2;           // 0..63
        const int j0 = (t & 3) * 16;
        f16 res[16];
        #pragma unroll
        for (int jj = 0; jj < 16; ++jj) {
            const int j = j0 + jj;
            const int tt = i - j + 63;   // 0..126
            float v = (float)sQE[i * 140 + tt] + (float)sKE[j * 140 + tt];
            res[jj] = (f16)v;
        }
        f16* dst = posb + ((size_t)bh * NL + l0 + i) * NL + r0 + j0;
        *(f16x8*)dst       = *(f16x8*)&res[0];
        *(f16x8*)(dst + 8) = *(f16x8*)&res[8];
    }
}

// ---------------------------------------------------------------------------
// Kernel C: f16-MFMA flash attention.  256 threads (4 waves), q-tile 32,
// k-tile 64, 3 barriers/kt, V double-buffered, A-frags resident in registers,
// struct/pos/mask prefetched one k-tile ahead.  LDS 41 KB -> 2 blocks/CU.
// ---------------------------------------------------------------------------
__global__ __launch_bounds__(256, 2) void attn_kernel(
    const f16* __restrict__ qf, const f16* __restrict__ kf,
    const f16* __restrict__ vt, const f16* __restrict__ qwf,
    const float* __restrict__ mask, const float* __restrict__ struct_m,
    const f16* __restrict__ posb, const float* __restrict__ abs_bias,
    float* __restrict__ out)
{
    __shared__ f16 sK[64 * 72];
    __shared__ f16 sVt[2][64 * 72];
    __shared__ float sS[32 * 68];
    __shared__ f16 sP[32 * 72];
    __shared__ float sAlpha[32], sL[32];

    const int l0 = blockIdx.x * 32;
    const int bh = blockIdx.y;
    const int bb = bh / NH, h = bh % NH;
    const int t  = threadIdx.x;
    const int lane  = t & 63;
    const int w     = t >> 6;       // 0..3
    const int quad  = lane >> 4;
    const int l15   = lane & 15;
    const int msub  = w >> 1;       // 0..1
    const int npair = w & 1;        // 0..1

    const size_t NQKV = (size_t)NB * NH * NL * DH;

    // ---- resident A-fragments (Q + 5 QW), loaded once from global ----
    f16x8 aQ[2], aW[5][2];
    {
        const size_t qrow = ((size_t)bh * NL + l0 + 16 * msub + l15) * DH;
        #pragma unroll
        for (int K = 0; K < 2; ++K) {
            aQ[K] = *(const f16x8*)&qf[qrow + 32 * K + 8 * quad];
            #pragma unroll
            for (int p = 0; p < 5; ++p)
                aW[p][K] = *(const f16x8*)&qwf[p * NQKV + qrow + 32 * K + 8 * quad];
        }
    }

    float ab[5];
    #pragma unroll
    for (int p = 0; p < 5; ++p) ab[p] = abs_bias[p * NH + h];

    // prefetch registers
    float pf_st[5][2][4], pf_pos[2][4], pf_mask[2];

    auto stage_kv = [&](int r0s, int buf) {
        const int row = t >> 3, col = (t & 7) * 8;
        const f16* ks = kf + ((size_t)bh * NL + r0s) * DH;
        *(f16x8*)&sK[row * 72 + col]        = *(const f16x8*)&ks[row * 64 + col];
        *(f16x8*)&sK[(row + 32) * 72 + col] = *(const f16x8*)&ks[(row + 32) * 64 + col];
        const f16* vs = vt + (size_t)bh * DH * NL + r0s;
        *(f16x8*)&sVt[buf][row * 72 + col] =
            *(const f16x8*)&vs[(size_t)row * NL + col];
        *(f16x8*)&sVt[buf][(row + 32) * 72 + col] =
            *(const f16x8*)&vs[(size_t)(row + 32) * NL + col];
    };

    auto prefetch = [&](int r0s) {
        #pragma unroll
        for (int n = 0; n < 2; ++n) {
            const int j = 32 * npair + 16 * n + l15;
            pf_mask[n] = mask[bb * NL + r0s + j];
            #pragma unroll
            for (int r = 0; r < 4; ++r) {
                const int i = 16 * msub + 4 * quad + r;
                pf_pos[n][r] = (float)posb[((size_t)bh * NL + l0 + i) * NL + r0s + j];
                #pragma unroll
                for (int p = 0; p < 5; ++p)
                    pf_st[p][n][r] =
                        struct_m[((size_t)(p * NB + bb) * NL + l0 + i) * NL + r0s + j];
            }
        }
    };

    stage_kv(0, 0);
    prefetch(0);

    const int sm_i = t >> 3;    // 0..31
    const int sm_jb = t & 7;
    float m_cur = -INFINITY, l_cur = 0.f;
    f32x4 O[2];
    O[0] = (f32x4){0.f, 0.f, 0.f, 0.f};
    O[1] = (f32x4){0.f, 0.f, 0.f, 0.f};

    for (int kt = 0; kt < 16; ++kt) {
        const int cur = kt & 1;
        __syncthreads();                   // staging of this kt complete

        // ---- Phase C: score MFMAs + epilogue ----
        {
            f32x4 acc[2][6];
            #pragma unroll
            for (int n = 0; n < 2; ++n)
                #pragma unroll
                for (int p = 0; p < 6; ++p)
                    acc[n][p] = (f32x4){0.f, 0.f, 0.f, 0.f};

            #pragma unroll
            for (int K = 0; K < 2; ++K) {
                const int koff = K * 32 + quad * 8;
                f16x8 bk[2];
                #pragma unroll
                for (int n = 0; n < 2; ++n)
                    bk[n] = *(f16x8*)&sK[(32 * npair + 16 * n + l15) * 72 + koff];
                #pragma unroll
                for (int n = 0; n < 2; ++n)
                    acc[n][0] = MFMA16(aQ[K], bk[n], acc[n][0]);
                #pragma unroll
                for (int p = 0; p < 5; ++p)
                    #pragma unroll
                    for (int n = 0; n < 2; ++n)
                        acc[n][1 + p] = MFMA16(aW[p][K], bk[n], acc[n][1 + p]);
            }

            #pragma unroll
            for (int n = 0; n < 2; ++n) {
                const int j = 32 * npair + 16 * n + l15;
                #pragma unroll
                for (int r = 0; r < 4; ++r) {
                    const int i = 16 * msub + 4 * quad + r;
                    float s = (acc[n][0][r] + pf_pos[n][r]) * 0.125f + pf_mask[n];
                    #pragma unroll
                    for (int p = 0; p < 5; ++p)
                        s += (acc[n][1 + p][r] + ab[p]) * pf_st[p][n][r];
                    sS[i * 68 + j] = s;
                }
            }
        }
        __syncthreads();                   // sS published

        // ---- Phase D: online softmax ----
        {
            float sv[8];
            float smax = -INFINITY;
            #pragma unroll
            for (int k = 0; k < 8; ++k) {
                sv[k] = sS[sm_i * 68 + sm_jb + 8 * k];
                smax = fmaxf(smax, sv[k]);
            }
            #pragma unroll
            for (int off = 4; off > 0; off >>= 1)
                smax = fmaxf(smax, __shfl_xor(smax, off, 8));
            const float m_new = fmaxf(m_cur, smax);
            const float alpha = __expf(m_cur - m_new);
            float rsum = 0.f;
            #pragma unroll
            for (int k = 0; k < 8; ++k) {
                float p = __expf(sv[k] - m_new);
                sP[sm_i * 72 + sm_jb + 8 * k] = (f16)p;
                rsum += p;
            }
            #pragma unroll
            for (int off = 4; off > 0; off >>= 1)
                rsum += __shfl_xor(rsum, off, 8);
            l_cur = l_cur * alpha + rsum;
            m_cur = m_new;
            if (sm_jb == 0) { sAlpha[sm_i] = alpha; sL[sm_i] = l_cur; }
        }
        __syncthreads();                   // sP/alpha published

        // ---- Phase E: PV MFMA + stage next + prefetch next ----
        {
            float a4[4];
            #pragma unroll
            for (int r = 0; r < 4; ++r) a4[r] = sAlpha[16 * msub + 4 * quad + r];
            #pragma unroll
            for (int n = 0; n < 2; ++n)
                #pragma unroll
                for (int r = 0; r < 4; ++r) O[n][r] *= a4[r];

            const int prow = (16 * msub + l15) * 72;
            #pragma unroll
            for (int K = 0; K < 2; ++K) {
                const int koff = K * 32 + quad * 8;
                f16x8 pfr = *(f16x8*)&sP[prow + koff];
                #pragma unroll
                for (int n = 0; n < 2; ++n) {
                    f16x8 vfr = *(f16x8*)&sVt[cur][(32 * npair + 16 * n + l15) * 72 + koff];
                    O[n] = MFMA16(pfr, vfr, O[n]);
                }
            }

            if (kt < 15) {
                stage_kv((kt + 1) * 64, cur ^ 1);
                prefetch((kt + 1) * 64);
            }
        }
    }

    // ---- final output ----
    float linv[4];
    #pragma unroll
    for (int r = 0; r < 4; ++r) linv[r] = 1.0f / sL[16 * msub + 4 * quad + r];
    #pragma unroll
    for (int n = 0; n < 2; ++n) {
        const int dh = 32 * npair + 16 * n + l15;
        #pragma unroll
        for (int r = 0; r < 4; ++r) {
            const int i = 16 * msub + 4 * quad + r;
            out[((size_t)bb * NL + l0 + i) * ND + h * DH + dh] = O[n][r] * linv[r];
        }
    }
}

// ---------------------------------------------------------------------------
extern "C" void kernel_launch(void* const* d_in, const int* in_sizes, int n_in,
                              void* d_out, int out_size, void* d_ws, size_t ws_size,
                              hipStream_t stream) {
    const float* hs   = (const float*)d_in[0];
    const float* mask = (const float*)d_in[1];
    const float* stm  = (const float*)d_in[2];
    const float* Wq   = (const float*)d_in[3];
    const float* bq   = (const float*)d_in[4];
    const float* Wk   = (const float*)d_in[5];
    const float* bk   = (const float*)d_in[6];
    const float* Wv   = (const float*)d_in[7];
    const float* bv   = (const float*)d_in[8];
    const float* de   = (const float*)d_in[9];
    const float* sw   = (const float*)d_in[10];
    const float* abb  = (const float*)d_in[11];
    float* outp = (float*)d_out;

    const size_t NQKV = (size_t)NB * NH * NL * DH;       // 1,572,864
    char* ws = (char*)d_ws;
    f16*   qf   = (f16*)ws;                 ws += NQKV * 2;
    f16*   kf   = (f16*)ws;                 ws += NQKV * 2;
    f16*   vtb  = (f16*)ws;                 ws += NQKV * 2;
    f16*   qwf  = (f16*)ws;                 ws += 5 * NQKV * 2;
    // qbuf (fp32, 6.3 MB) overlaid at the start of the posb region (50.3 MB);
    // qbuf is dead after qw_kernel, pos_kernel then overwrites the region.
    float* qbuf = (float*)ws;
    f16*   posb = (f16*)ws;                 // 24*1024*1024 f16

    qkv_kernel<<<dim3(32, 36), 256, 0, stream>>>(hs, Wq, bq, Wk, bk, Wv, bv,
                                                 qbuf, qf, kf, vtb);
    qw_kernel<<<dim3(16, 120), 256, 0, stream>>>(qbuf, sw, qwf);
    pos_kernel<<<dim3(16, 16, 24), 256, 0, stream>>>(qf, kf, de, posb);
    attn_kernel<<<dim3(32, 24), 256, 0, stream>>>(qf, kf, vtb, qwf,
                                                  mask, stm, posb, abb, outp);
}

// Round 4
// 247.715 us; speedup vs baseline: 3.9916x; 1.3970x over previous
//
#include <hip/hip_runtime.h>
#include <math.h>

#define NB 2
#define NL 1024
#define ND 768
#define NH 12
#define DH 64

typedef _Float16 f16;
typedef _Float16 f16x4 __attribute__((ext_vector_type(4)));
typedef _Float16 f16x8 __attribute__((ext_vector_type(8)));
typedef float f32x4 __attribute__((ext_vector_type(4)));

#define MFMA16(a, b, c) __builtin_amdgcn_mfma_f32_16x16x32_f16((a), (b), (c), 0, 0, 0)

// ---------------------------------------------------------------------------
// Kernel 0: prep.
//   tiles 0..767    : hs fp32 -> hsf f16 (straight convert)
//   tiles 768..1199 : W{q,k,v} [768k][768n] fp32 -> wt f16 [(mat*12+h)*64+n][k]
//   tiles 1200..1259: ssan_w [p][h][64d][64e] fp32 -> swt f16 [p][h][e][d]
// Transposes via LDS bounce (pad 66 fp32; scalar transposed writes ~4-way,
// float2 coalesced reads 2-way=free).
// ---------------------------------------------------------------------------
__global__ __launch_bounds__(256) void prep_kernel(
    const float* __restrict__ hs,
    const float* __restrict__ Wq, const float* __restrict__ Wk,
    const float* __restrict__ Wv, const float* __restrict__ sw,
    f16* __restrict__ hsf, f16* __restrict__ wt, f16* __restrict__ swt)
{
    __shared__ float sT[64 * 66];
    const int t = threadIdx.x;
    const int tile = blockIdx.x;

    if (tile < 768) {
        const int base = tile * 2048 + t * 8;
        float4 a = *(const float4*)&hs[base];
        float4 b = *(const float4*)&hs[base + 4];
        f16x8 hv;
        hv[0] = (f16)a.x; hv[1] = (f16)a.y; hv[2] = (f16)a.z; hv[3] = (f16)a.w;
        hv[4] = (f16)b.x; hv[5] = (f16)b.y; hv[6] = (f16)b.z; hv[7] = (f16)b.w;
        *(f16x8*)&hsf[base] = hv;
        return;
    }

    const float* S; f16* D; int sRS, dRS;
    const int ti = tile - 768;
    if (ti < 432) {
        const int mat = ti / 144, r2 = ti % 144, ht = r2 / 12, kt = r2 % 12;
        const float* W = (mat == 0) ? Wq : (mat == 1) ? Wk : Wv;
        S = W + (size_t)(kt * 64) * ND + ht * 64;              // S[kk*768 + n]
        D = wt + (size_t)((mat * NH + ht) * 64) * ND + kt * 64; // D[n*768 + kk]
        sRS = ND; dRS = ND;
    } else {
        const int i = ti - 432;                                // p*12+h
        S = sw + (size_t)i * 4096;                             // S[d*64 + e]
        D = swt + (size_t)i * 4096;                            // D[e*64 + d]
        sRS = 64; dRS = 64;
    }

    {
        const int kk = t >> 2, nb = (t & 3) * 16;
        float v[16];
        #pragma unroll
        for (int j = 0; j < 4; ++j)
            *(float4*)&v[4 * j] = *(const float4*)&S[(size_t)kk * sRS + nb + 4 * j];
        #pragma unroll
        for (int jj = 0; jj < 16; ++jj)
            sT[(nb + jj) * 66 + kk] = v[jj];
    }
    __syncthreads();
    {
        const int n = t >> 2, kb = (t & 3) * 16;
        f16 tmp[16];
        #pragma unroll
        for (int j = 0; j < 8; ++j) {
            float2 x = *(float2*)&sT[n * 66 + kb + 2 * j];
            tmp[2 * j]     = (f16)x.x;
            tmp[2 * j + 1] = (f16)x.y;
        }
        *(f16x8*)&D[(size_t)n * dRS + kb]     = *(f16x8*)&tmp[0];
        *(f16x8*)&D[(size_t)n * dRS + kb + 8] = *(f16x8*)&tmp[8];
    }
}

// ---------------------------------------------------------------------------
// Kernel A: QKV projection, f16 MFMA.  64x64 tile, 4 waves, 2x2 subtiles/wave.
//   mat0 -> qf [bh][l][d], mat1 -> kf, mat2 -> vt [bh][d][l] (transposed).
// ---------------------------------------------------------------------------
__global__ __launch_bounds__(256, 4) void qkv_kernel(
    const f16* __restrict__ hsf, const f16* __restrict__ wt,
    const float* __restrict__ bq, const float* __restrict__ bk,
    const float* __restrict__ bv,
    f16* __restrict__ qf, f16* __restrict__ kf, f16* __restrict__ vt)
{
    __shared__ f16 sA[64 * 72], sB[64 * 72];
    __shared__ float sT[64 * 66];

    const int m0  = blockIdx.x * 64;
    const int y   = blockIdx.y;          // 0..35
    const int mat = y / NH, h = y % NH;
    const int t = threadIdx.x, lane = t & 63, w = t >> 6;
    const int quad = lane >> 4, l15 = lane & 15;
    const int wm = w >> 1, wn = w & 1;

    const float* bias = (mat == 0) ? bq : (mat == 1) ? bk : bv;

    f32x4 acc[2][2];
    #pragma unroll
    for (int r = 0; r < 2; ++r)
        #pragma unroll
        for (int c = 0; c < 2; ++c) acc[r][c] = (f32x4){0.f, 0.f, 0.f, 0.f};

    const int srow = t >> 2, scol = (t & 3) * 16;
    const f16* Ag = hsf + (size_t)(m0 + srow) * ND + scol;
    const f16* Bg = wt + ((size_t)y * 64 + srow) * ND + scol;

    for (int k0 = 0; k0 < ND; k0 += 64) {
        __syncthreads();
        *(f16x8*)&sA[srow * 72 + scol]     = *(const f16x8*)&Ag[k0];
        *(f16x8*)&sA[srow * 72 + scol + 8] = *(const f16x8*)&Ag[k0 + 8];
        *(f16x8*)&sB[srow * 72 + scol]     = *(const f16x8*)&Bg[k0];
        *(f16x8*)&sB[srow * 72 + scol + 8] = *(const f16x8*)&Bg[k0 + 8];
        __syncthreads();
        #pragma unroll
        for (int kk = 0; kk < 64; kk += 32) {
            const int ko = kk + quad * 8;
            f16x8 a0 = *(f16x8*)&sA[(32 * wm + l15) * 72 + ko];
            f16x8 a1 = *(f16x8*)&sA[(32 * wm + 16 + l15) * 72 + ko];
            f16x8 b0 = *(f16x8*)&sB[(32 * wn + l15) * 72 + ko];
            f16x8 b1 = *(f16x8*)&sB[(32 * wn + 16 + l15) * 72 + ko];
            acc[0][0] = MFMA16(a0, b0, acc[0][0]);
            acc[0][1] = MFMA16(a0, b1, acc[0][1]);
            acc[1][0] = MFMA16(a1, b0, acc[1][0]);
            acc[1][1] = MFMA16(a1, b1, acc[1][1]);
        }
    }
    __syncthreads();

    const int bb = m0 >> 10;
    const int lbase = m0 & 1023;
    const int bh = bb * NH + h;

    if (mat < 2) {
        #pragma unroll
        for (int r = 0; r < 2; ++r)
            #pragma unroll
            for (int c = 0; c < 2; ++c) {
                const int col = 32 * wn + 16 * c + l15;
                const float bz = bias[h * 64 + col];
                #pragma unroll
                for (int rr = 0; rr < 4; ++rr)
                    sT[(32 * wm + 16 * r + 4 * quad + rr) * 66 + col] = acc[r][c][rr] + bz;
            }
        __syncthreads();
        const int orow = t >> 2, ocb = (t & 3) * 16;
        f16 tmp[16];
        #pragma unroll
        for (int j = 0; j < 8; ++j) {
            float2 x = *(float2*)&sT[orow * 66 + ocb + 2 * j];
            tmp[2 * j] = (f16)x.x; tmp[2 * j + 1] = (f16)x.y;
        }
        f16* dst = ((mat == 0) ? qf : kf) + ((size_t)bh * NL + lbase + orow) * DH + ocb;
        *(f16x8*)dst       = *(f16x8*)&tmp[0];
        *(f16x8*)(dst + 8) = *(f16x8*)&tmp[8];
    } else {
        #pragma unroll
        for (int r = 0; r < 2; ++r)
            #pragma unroll
            for (int c = 0; c < 2; ++c) {
                const int col = 32 * wn + 16 * c + l15;
                const float bz = bias[h * 64 + col];
                #pragma unroll
                for (int rr = 0; rr < 4; ++rr)
                    sT[col * 66 + 32 * wm + 16 * r + 4 * quad + rr] = acc[r][c][rr] + bz;
            }
        __syncthreads();
        const int d = t >> 2, lcb = (t & 3) * 16;
        f16 tmp[16];
        #pragma unroll
        for (int j = 0; j < 8; ++j) {
            float2 x = *(float2*)&sT[d * 66 + lcb + 2 * j];
            tmp[2 * j] = (f16)x.x; tmp[2 * j + 1] = (f16)x.y;
        }
        f16* dst = vt + ((size_t)bh * DH + d) * NL + lbase + lcb;
        *(f16x8*)dst       = *(f16x8*)&tmp[0];
        *(f16x8*)(dst + 8) = *(f16x8*)&tmp[8];
    }
}

// ---------------------------------------------------------------------------
// Kernel B: qw[p,bh,l,e] = qf[bh,l,:] @ ssan_w[p,h]  via f16 MFMA (K=64).
// ---------------------------------------------------------------------------
__global__ __launch_bounds__(256, 4) void qw_kernel(
    const f16* __restrict__ qf, const f16* __restrict__ swt,
    f16* __restrict__ qwf)
{
    __shared__ f16 sA[64 * 72], sB[64 * 72];
    __shared__ float sT[64 * 66];

    const int l0 = blockIdx.x * 64;
    const int z  = blockIdx.y;      // 0..119
    const int p  = z / 24, bh = z % 24, h = bh % NH;
    const int t = threadIdx.x, lane = t & 63, w = t >> 6;
    const int quad = lane >> 4, l15 = lane & 15;
    const int wm = w >> 1, wn = w & 1;

    const int srow = t >> 2, scol = (t & 3) * 16;
    {
        const f16* As = qf + ((size_t)bh * NL + l0 + srow) * DH + scol;
        const f16* Bs = swt + ((size_t)(p * NH + h) * 64 + srow) * 64 + scol;
        *(f16x8*)&sA[srow * 72 + scol]     = *(const f16x8*)As;
        *(f16x8*)&sA[srow * 72 + scol + 8] = *(const f16x8*)(As + 8);
        *(f16x8*)&sB[srow * 72 + scol]     = *(const f16x8*)Bs;
        *(f16x8*)&sB[srow * 72 + scol + 8] = *(const f16x8*)(Bs + 8);
    }
    __syncthreads();

    f32x4 acc[2][2];
    #pragma unroll
    for (int r = 0; r < 2; ++r)
        #pragma unroll
        for (int c = 0; c < 2; ++c) acc[r][c] = (f32x4){0.f, 0.f, 0.f, 0.f};

    #pragma unroll
    for (int kk = 0; kk < 64; kk += 32) {
        const int ko = kk + quad * 8;
        f16x8 a0 = *(f16x8*)&sA[(32 * wm + l15) * 72 + ko];
        f16x8 a1 = *(f16x8*)&sA[(32 * wm + 16 + l15) * 72 + ko];
        f16x8 b0 = *(f16x8*)&sB[(32 * wn + l15) * 72 + ko];
        f16x8 b1 = *(f16x8*)&sB[(32 * wn + 16 + l15) * 72 + ko];
        acc[0][0] = MFMA16(a0, b0, acc[0][0]);
        acc[0][1] = MFMA16(a0, b1, acc[0][1]);
        acc[1][0] = MFMA16(a1, b0, acc[1][0]);
        acc[1][1] = MFMA16(a1, b1, acc[1][1]);
    }
    __syncthreads();

    #pragma unroll
    for (int r = 0; r < 2; ++r)
        #pragma unroll
        for (int c = 0; c < 2; ++c) {
            const int col = 32 * wn + 16 * c + l15;
            #pragma unroll
            for (int rr = 0; rr < 4; ++rr)
                sT[(32 * wm + 16 * r + 4 * quad + rr) * 66 + col] = acc[r][c][rr];
        }
    __syncthreads();

    const int orow = t >> 2, ocb = (t & 3) * 16;
    f16 tmp[16];
    #pragma unroll
    for (int j = 0; j < 8; ++j) {
        float2 x = *(float2*)&sT[orow * 66 + ocb + 2 * j];
        tmp[2 * j] = (f16)x.x; tmp[2 * j + 1] = (f16)x.y;
    }
    f16* dst = qwf + ((size_t)(p * 24 + bh) * NL + l0 + orow) * DH + ocb;
    *(f16x8*)dst       = *(f16x8*)&tmp[0];
    *(f16x8*)(dst + 8) = *(f16x8*)&tmp[8];
}

// ---------------------------------------------------------------------------
// Kernel P: posb[bh][l][r] = (q[bh,l] + k[bh,r]) . dist_emb[l-r+1023]   (f16)
// ---------------------------------------------------------------------------
__global__ __launch_bounds__(256, 2) void pos_kernel(
    const f16* __restrict__ qf, const f16* __restrict__ kf,
    const float* __restrict__ dist_emb, f16* __restrict__ posb)
{
    __shared__ f16 sQ[64 * 72], sK2[64 * 72];
    __shared__ f16 sE[128 * 72];
    __shared__ f16 sQE[64 * 140], sKE[64 * 140];

    const int l0 = blockIdx.x * 64;
    const int r0 = blockIdx.y * 64;
    const int bh = blockIdx.z;
    const int t  = threadIdx.x;
    const int lane = t & 63;
    const int w    = t >> 6;       // 0..3
    const int quad = lane >> 4;
    const int l15  = lane & 15;

    {
        const int row = t >> 3, col = (t & 7) * 8;
        const f16* qs = qf + ((size_t)bh * NL + l0) * DH;
        const f16* ks = kf + ((size_t)bh * NL + r0) * DH;
        *(f16x8*)&sQ[row * 72 + col]        = *(const f16x8*)&qs[row * 64 + col];
        *(f16x8*)&sQ[(row + 32) * 72 + col] = *(const f16x8*)&qs[(row + 32) * 64 + col];
        *(f16x8*)&sK2[row * 72 + col]        = *(const f16x8*)&ks[row * 64 + col];
        *(f16x8*)&sK2[(row + 32) * 72 + col] = *(const f16x8*)&ks[(row + 32) * 64 + col];
        const int ebase = l0 - r0 + 960;
        #pragma unroll
        for (int p = 0; p < 4; ++p) {
            const int er = row + 32 * p;
            if (er < 127) {
                const float* es = dist_emb + (size_t)(ebase + er) * DH + col;
                float4 a = *(const float4*)es;
                float4 b = *(const float4*)(es + 4);
                f16x8 hv;
                hv[0] = (f16)a.x; hv[1] = (f16)a.y; hv[2] = (f16)a.z; hv[3] = (f16)a.w;
                hv[4] = (f16)b.x; hv[5] = (f16)b.y; hv[6] = (f16)b.z; hv[7] = (f16)b.w;
                *(f16x8*)&sE[er * 72 + col] = hv;
            }
        }
    }
    __syncthreads();

    {
        const int arow = (16 * w + l15) * 72 + quad * 8;
        f16x8 aq0 = *(f16x8*)&sQ[arow];
        f16x8 aq1 = *(f16x8*)&sQ[arow + 32];
        f16x8 ak0 = *(f16x8*)&sK2[arow];
        f16x8 ak1 = *(f16x8*)&sK2[arow + 32];
        #pragma unroll
        for (int n = 0; n < 8; ++n) {
            const int brow = (16 * n + l15) * 72 + quad * 8;
            f16x8 e0 = *(f16x8*)&sE[brow];
            f16x8 e1 = *(f16x8*)&sE[brow + 32];
            f32x4 cq = {0.f, 0.f, 0.f, 0.f};
            cq = MFMA16(aq0, e0, cq);
            cq = MFMA16(aq1, e1, cq);
            f32x4 ck = {0.f, 0.f, 0.f, 0.f};
            ck = MFMA16(ak0, e0, ck);
            ck = MFMA16(ak1, e1, ck);
            #pragma unroll
            for (int r = 0; r < 4; ++r) {
                sQE[(16 * w + 4 * quad + r) * 140 + 16 * n + l15] = (f16)cq[r];
                sKE[(16 * w + 4 * quad + r) * 140 + 16 * n + l15] = (f16)ck[r];
            }
        }
    }
    __syncthreads();

    {
        const int i  = t >> 2;           // 0..63
        const int j0 = (t & 3) * 16;
        f16 res[16];
        #pragma unroll
        for (int jj = 0; jj < 16; ++jj) {
            const int j = j0 + jj;
            const int tt = i - j + 63;   // 0..126
            float v = (float)sQE[i * 140 + tt] + (float)sKE[j * 140 + tt];
            res[jj] = (f16)v;
        }
        f16* dst = posb + ((size_t)bh * NL + l0 + i) * NL + r0 + j0;
        *(f16x8*)dst       = *(f16x8*)&res[0];
        *(f16x8*)(dst + 8) = *(f16x8*)&res[8];
    }
}

// ---------------------------------------------------------------------------
// Kernel C: f16-MFMA flash attention (unchanged from round 3).
// ---------------------------------------------------------------------------
__global__ __launch_bounds__(256, 2) void attn_kernel(
    const f16* __restrict__ qf, const f16* __restrict__ kf,
    const f16* __restrict__ vt, const f16* __restrict__ qwf,
    const float* __restrict__ mask, const float* __restrict__ struct_m,
    const f16* __restrict__ posb, const float* __restrict__ abs_bias,
    float* __restrict__ out)
{
    __shared__ f16 sK[64 * 72];
    __shared__ f16 sVt[2][64 * 72];
    __shared__ float sS[32 * 68];
    __shared__ f16 sP[32 * 72];
    __shared__ float sAlpha[32], sL[32];

    const int l0 = blockIdx.x * 32;
    const int bh = blockIdx.y;
    const int bb = bh / NH, h = bh % NH;
    const int t  = threadIdx.x;
    const int lane  = t & 63;
    const int w     = t >> 6;       // 0..3
    const int quad  = lane >> 4;
    const int l15   = lane & 15;
    const int msub  = w >> 1;       // 0..1
    const int npair = w & 1;        // 0..1

    const size_t NQKV = (size_t)NB * NH * NL * DH;

    f16x8 aQ[2], aW[5][2];
    {
        const size_t qrow = ((size_t)bh * NL + l0 + 16 * msub + l15) * DH;
        #pragma unroll
        for (int K = 0; K < 2; ++K) {
            aQ[K] = *(const f16x8*)&qf[qrow + 32 * K + 8 * quad];
            #pragma unroll
            for (int p = 0; p < 5; ++p)
                aW[p][K] = *(const f16x8*)&qwf[p * NQKV + qrow + 32 * K + 8 * quad];
        }
    }

    float ab[5];
    #pragma unroll
    for (int p = 0; p < 5; ++p) ab[p] = abs_bias[p * NH + h];

    float pf_st[5][2][4], pf_pos[2][4], pf_mask[2];

    auto stage_kv = [&](int r0s, int buf) {
        const int row = t >> 3, col = (t & 7) * 8;
        const f16* ks = kf + ((size_t)bh * NL + r0s) * DH;
        *(f16x8*)&sK[row * 72 + col]        = *(const f16x8*)&ks[row * 64 + col];
        *(f16x8*)&sK[(row + 32) * 72 + col] = *(const f16x8*)&ks[(row + 32) * 64 + col];
        const f16* vs = vt + (size_t)bh * DH * NL + r0s;
        *(f16x8*)&sVt[buf][row * 72 + col] =
            *(const f16x8*)&vs[(size_t)row * NL + col];
        *(f16x8*)&sVt[buf][(row + 32) * 72 + col] =
            *(const f16x8*)&vs[(size_t)(row + 32) * NL + col];
    };

    auto prefetch = [&](int r0s) {
        #pragma unroll
        for (int n = 0; n < 2; ++n) {
            const int j = 32 * npair + 16 * n + l15;
            pf_mask[n] = mask[bb * NL + r0s + j];
            #pragma unroll
            for (int r = 0; r < 4; ++r) {
                const int i = 16 * msub + 4 * quad + r;
                pf_pos[n][r] = (float)posb[((size_t)bh * NL + l0 + i) * NL + r0s + j];
                #pragma unroll
                for (int p = 0; p < 5; ++p)
                    pf_st[p][n][r] =
                        struct_m[((size_t)(p * NB + bb) * NL + l0 + i) * NL + r0s + j];
            }
        }
    };

    stage_kv(0, 0);
    prefetch(0);

    const int sm_i = t >> 3;
    const int sm_jb = t & 7;
    float m_cur = -INFINITY, l_cur = 0.f;
    f32x4 O[2];
    O[0] = (f32x4){0.f, 0.f, 0.f, 0.f};
    O[1] = (f32x4){0.f, 0.f, 0.f, 0.f};

    for (int kt = 0; kt < 16; ++kt) {
        const int cur = kt & 1;
        __syncthreads();

        {
            f32x4 acc[2][6];
            #pragma unroll
            for (int n = 0; n < 2; ++n)
                #pragma unroll
                for (int p = 0; p < 6; ++p)
                    acc[n][p] = (f32x4){0.f, 0.f, 0.f, 0.f};

            #pragma unroll
            for (int K = 0; K < 2; ++K) {
                const int koff = K * 32 + quad * 8;
                f16x8 bk2[2];
                #pragma unroll
                for (int n = 0; n < 2; ++n)
                    bk2[n] = *(f16x8*)&sK[(32 * npair + 16 * n + l15) * 72 + koff];
                #pragma unroll
                for (int n = 0; n < 2; ++n)
                    acc[n][0] = MFMA16(aQ[K], bk2[n], acc[n][0]);
                #pragma unroll
                for (int p = 0; p < 5; ++p)
                    #pragma unroll
                    for (int n = 0; n < 2; ++n)
                        acc[n][1 + p] = MFMA16(aW[p][K], bk2[n], acc[n][1 + p]);
            }

            #pragma unroll
            for (int n = 0; n < 2; ++n) {
                const int j = 32 * npair + 16 * n + l15;
                #pragma unroll
                for (int r = 0; r < 4; ++r) {
                    const int i = 16 * msub + 4 * quad + r;
                    float s = (acc[n][0][r] + pf_pos[n][r]) * 0.125f + pf_mask[n];
                    #pragma unroll
                    for (int p = 0; p < 5; ++p)
                        s += (acc[n][1 + p][r] + ab[p]) * pf_st[p][n][r];
                    sS[i * 68 + j] = s;
                }
            }
        }
        __syncthreads();

        {
            float sv[8];
            float smax = -INFINITY;
            #pragma unroll
            for (int k = 0; k < 8; ++k) {
                sv[k] = sS[sm_i * 68 + sm_jb + 8 * k];
                smax = fmaxf(smax, sv[k]);
            }
            #pragma unroll
            for (int off = 4; off > 0; off >>= 1)
                smax = fmaxf(smax, __shfl_xor(smax, off, 8));
            const float m_new = fmaxf(m_cur, smax);
            const float alpha = __expf(m_cur - m_new);
            float rsum = 0.f;
            #pragma unroll
            for (int k = 0; k < 8; ++k) {
                float p = __expf(sv[k] - m_new);
                sP[sm_i * 72 + sm_jb + 8 * k] = (f16)p;
                rsum += p;
            }
            #pragma unroll
            for (int off = 4; off > 0; off >>= 1)
                rsum += __shfl_xor(rsum, off, 8);
            l_cur = l_cur * alpha + rsum;
            m_cur = m_new;
            if (sm_jb == 0) { sAlpha[sm_i] = alpha; sL[sm_i] = l_cur; }
        }
        __syncthreads();

        {
            float a4[4];
            #pragma unroll
            for (int r = 0; r < 4; ++r) a4[r] = sAlpha[16 * msub + 4 * quad + r];
            #pragma unroll
            for (int n = 0; n < 2; ++n)
                #pragma unroll
                for (int r = 0; r < 4; ++r) O[n][r] *= a4[r];

            const int prow = (16 * msub + l15) * 72;
            #pragma unroll
            for (int K = 0; K < 2; ++K) {
                const int koff = K * 32 + quad * 8;
                f16x8 pfr = *(f16x8*)&sP[prow + koff];
                #pragma unroll
                for (int n = 0; n < 2; ++n) {
                    f16x8 vfr = *(f16x8*)&sVt[cur][(32 * npair + 16 * n + l15) * 72 + koff];
                    O[n] = MFMA16(pfr, vfr, O[n]);
                }
            }

            if (kt < 15) {
                stage_kv((kt + 1) * 64, cur ^ 1);
                prefetch((kt + 1) * 64);
            }
        }
    }

    float linv[4];
    #pragma unroll
    for (int r = 0; r < 4; ++r) linv[r] = 1.0f / sL[16 * msub + 4 * quad + r];
    #pragma unroll
    for (int n = 0; n < 2; ++n) {
        const int dh = 32 * npair + 16 * n + l15;
        #pragma unroll
        for (int r = 0; r < 4; ++r) {
            const int i = 16 * msub + 4 * quad + r;
            out[((size_t)bb * NL + l0 + i) * ND + h * DH + dh] = O[n][r] * linv[r];
        }
    }
}

// ---------------------------------------------------------------------------
extern "C" void kernel_launch(void* const* d_in, const int* in_sizes, int n_in,
                              void* d_out, int out_size, void* d_ws, size_t ws_size,
                              hipStream_t stream) {
    const float* hs   = (const float*)d_in[0];
    const float* mask = (const float*)d_in[1];
    const float* stm  = (const float*)d_in[2];
    const float* Wq   = (const float*)d_in[3];
    const float* bq   = (const float*)d_in[4];
    const float* Wk   = (const float*)d_in[5];
    const float* bk   = (const float*)d_in[6];
    const float* Wv   = (const float*)d_in[7];
    const float* bv   = (const float*)d_in[8];
    const float* de   = (const float*)d_in[9];
    const float* sw   = (const float*)d_in[10];
    const float* abb  = (const float*)d_in[11];
    float* outp = (float*)d_out;

    const size_t NQKV = (size_t)NB * NH * NL * DH;       // 1,572,864
    char* ws = (char*)d_ws;
    f16* qf   = (f16*)ws;                 ws += NQKV * 2;
    f16* kf   = (f16*)ws;                 ws += NQKV * 2;
    f16* vtb  = (f16*)ws;                 ws += NQKV * 2;
    f16* qwf  = (f16*)ws;                 ws += 5 * NQKV * 2;
    f16* posb = (f16*)ws;                 // 24*1024*1024 f16 = 50.3 MB
    // hsf/wt/swt overlay the posb region: they are dead before pos_kernel
    // (stream-ordered) overwrites it.
    f16* hsf = posb;                        // 1,572,864 f16
    f16* wt  = hsf + NQKV;                  // 2304*768 = 1,769,472 f16
    f16* swt = wt + (size_t)2304 * 768;     // 245,760 f16

    prep_kernel<<<1260, 256, 0, stream>>>(hs, Wq, Wk, Wv, sw, hsf, wt, swt);
    qkv_kernel<<<dim3(32, 36), 256, 0, stream>>>(hsf, wt, bq, bk, bv, qf, kf, vtb);
    qw_kernel<<<dim3(16, 120), 256, 0, stream>>>(qf, swt, qwf);
    pos_kernel<<<dim3(16, 16, 24), 256, 0, stream>>>(qf, kf, de, posb);
    attn_kernel<<<dim3(32, 24), 256, 0, stream>>>(qf, kf, vtb, qwf,
                                                  mask, stm, posb, abb, outp);
}

// Round 5
// 245.984 us; speedup vs baseline: 4.0197x; 1.0070x over previous
//
#include <hip/hip_runtime.h>
#include <math.h>

#define NB 2
#define NL 1024
#define ND 768
#define NH 12
#define DH 64

typedef _Float16 f16;
typedef _Float16 f16x4 __attribute__((ext_vector_type(4)));
typedef _Float16 f16x8 __attribute__((ext_vector_type(8)));
typedef float f32x4 __attribute__((ext_vector_type(4)));

#define MFMA16(a, b, c) __builtin_amdgcn_mfma_f32_16x16x32_f16((a), (b), (c), 0, 0, 0)

// Barrier that orders LDS traffic but does NOT drain outstanding global
// loads (vmcnt). All inter-thread communication in these kernels is via
// LDS; register-destined global loads get their use-site s_waitcnt from
// the compiler automatically. This avoids the ~900-cycle HBM drain the
// compiler's __syncthreads() (s_waitcnt vmcnt(0)) forces at every barrier.
__device__ __forceinline__ void soft_barrier() {
    asm volatile("s_waitcnt lgkmcnt(0)\n\ts_barrier" ::: "memory");
}

// ---------------------------------------------------------------------------
// Kernel 0: prep.
//   tiles 0..767    : hs fp32 -> hsf f16
//   tiles 768..1199 : W{q,k,v} -> wt f16 [(mat*12+h)*64+n][k]   (transposed)
//   tiles 1200..1259: ssan_w -> swt f16 [p][h][e][d]            (transposed)
//   tiles 1260..1323: dist_emb fp32 -> de16 f16
// ---------------------------------------------------------------------------
__global__ __launch_bounds__(256) void prep_kernel(
    const float* __restrict__ hs,
    const float* __restrict__ Wq, const float* __restrict__ Wk,
    const float* __restrict__ Wv, const float* __restrict__ sw,
    const float* __restrict__ de,
    f16* __restrict__ hsf, f16* __restrict__ wt, f16* __restrict__ swt,
    f16* __restrict__ de16)
{
    __shared__ float sT[64 * 66];
    const int t = threadIdx.x;
    const int tile = blockIdx.x;

    if (tile < 768) {
        const int base = tile * 2048 + t * 8;
        float4 a = *(const float4*)&hs[base];
        float4 b = *(const float4*)&hs[base + 4];
        f16x8 hv;
        hv[0] = (f16)a.x; hv[1] = (f16)a.y; hv[2] = (f16)a.z; hv[3] = (f16)a.w;
        hv[4] = (f16)b.x; hv[5] = (f16)b.y; hv[6] = (f16)b.z; hv[7] = (f16)b.w;
        *(f16x8*)&hsf[base] = hv;
        return;
    }
    if (tile >= 1260) {
        const int base = (tile - 1260) * 2048 + t * 8;
        if (base < 2047 * 64) {
            float4 a = *(const float4*)&de[base];
            float4 b = *(const float4*)&de[base + 4];
            f16x8 hv;
            hv[0] = (f16)a.x; hv[1] = (f16)a.y; hv[2] = (f16)a.z; hv[3] = (f16)a.w;
            hv[4] = (f16)b.x; hv[5] = (f16)b.y; hv[6] = (f16)b.z; hv[7] = (f16)b.w;
            *(f16x8*)&de16[base] = hv;
        }
        return;
    }

    const float* S; f16* D; int sRS, dRS;
    const int ti = tile - 768;
    if (ti < 432) {
        const int mat = ti / 144, r2 = ti % 144, ht = r2 / 12, kt = r2 % 12;
        const float* W = (mat == 0) ? Wq : (mat == 1) ? Wk : Wv;
        S = W + (size_t)(kt * 64) * ND + ht * 64;
        D = wt + (size_t)((mat * NH + ht) * 64) * ND + kt * 64;
        sRS = ND; dRS = ND;
    } else {
        const int i = ti - 432;
        S = sw + (size_t)i * 4096;
        D = swt + (size_t)i * 4096;
        sRS = 64; dRS = 64;
    }

    {
        const int kk = t >> 2, nb = (t & 3) * 16;
        float v[16];
        #pragma unroll
        for (int j = 0; j < 4; ++j)
            *(float4*)&v[4 * j] = *(const float4*)&S[(size_t)kk * sRS + nb + 4 * j];
        #pragma unroll
        for (int jj = 0; jj < 16; ++jj)
            sT[(nb + jj) * 66 + kk] = v[jj];
    }
    soft_barrier();
    {
        const int n = t >> 2, kb = (t & 3) * 16;
        f16 tmp[16];
        #pragma unroll
        for (int j = 0; j < 8; ++j) {
            float2 x = *(float2*)&sT[n * 66 + kb + 2 * j];
            tmp[2 * j]     = (f16)x.x;
            tmp[2 * j + 1] = (f16)x.y;
        }
        *(f16x8*)&D[(size_t)n * dRS + kb]     = *(f16x8*)&tmp[0];
        *(f16x8*)&D[(size_t)n * dRS + kb + 8] = *(f16x8*)&tmp[8];
    }
}

// ---------------------------------------------------------------------------
// Kernel A: QKV projection, f16 MFMA.  64x64 tile, 4 waves, 2x2 subtiles/wave.
// ---------------------------------------------------------------------------
__global__ __launch_bounds__(256, 4) void qkv_kernel(
    const f16* __restrict__ hsf, const f16* __restrict__ wt,
    const float* __restrict__ bq, const float* __restrict__ bk,
    const float* __restrict__ bv,
    f16* __restrict__ qf, f16* __restrict__ kf, f16* __restrict__ vt)
{
    __shared__ f16 sA[64 * 72], sB[64 * 72];
    __shared__ float sT[64 * 66];

    const int m0  = blockIdx.x * 64;
    const int y   = blockIdx.y;          // 0..35
    const int mat = y / NH, h = y % NH;
    const int t = threadIdx.x, lane = t & 63, w = t >> 6;
    const int quad = lane >> 4, l15 = lane & 15;
    const int wm = w >> 1, wn = w & 1;

    const float* bias = (mat == 0) ? bq : (mat == 1) ? bk : bv;

    f32x4 acc[2][2];
    #pragma unroll
    for (int r = 0; r < 2; ++r)
        #pragma unroll
        for (int c = 0; c < 2; ++c) acc[r][c] = (f32x4){0.f, 0.f, 0.f, 0.f};

    const int srow = t >> 2, scol = (t & 3) * 16;
    const f16* Ag = hsf + (size_t)(m0 + srow) * ND + scol;
    const f16* Bg = wt + ((size_t)y * 64 + srow) * ND + scol;

    for (int k0 = 0; k0 < ND; k0 += 64) {
        soft_barrier();
        *(f16x8*)&sA[srow * 72 + scol]     = *(const f16x8*)&Ag[k0];
        *(f16x8*)&sA[srow * 72 + scol + 8] = *(const f16x8*)&Ag[k0 + 8];
        *(f16x8*)&sB[srow * 72 + scol]     = *(const f16x8*)&Bg[k0];
        *(f16x8*)&sB[srow * 72 + scol + 8] = *(const f16x8*)&Bg[k0 + 8];
        soft_barrier();
        #pragma unroll
        for (int kk = 0; kk < 64; kk += 32) {
            const int ko = kk + quad * 8;
            f16x8 a0 = *(f16x8*)&sA[(32 * wm + l15) * 72 + ko];
            f16x8 a1 = *(f16x8*)&sA[(32 * wm + 16 + l15) * 72 + ko];
            f16x8 b0 = *(f16x8*)&sB[(32 * wn + l15) * 72 + ko];
            f16x8 b1 = *(f16x8*)&sB[(32 * wn + 16 + l15) * 72 + ko];
            acc[0][0] = MFMA16(a0, b0, acc[0][0]);
            acc[0][1] = MFMA16(a0, b1, acc[0][1]);
            acc[1][0] = MFMA16(a1, b0, acc[1][0]);
            acc[1][1] = MFMA16(a1, b1, acc[1][1]);
        }
    }
    soft_barrier();

    const int bb = m0 >> 10;
    const int lbase = m0 & 1023;
    const int bh = bb * NH + h;

    if (mat < 2) {
        #pragma unroll
        for (int r = 0; r < 2; ++r)
            #pragma unroll
            for (int c = 0; c < 2; ++c) {
                const int col = 32 * wn + 16 * c + l15;
                const float bz = bias[h * 64 + col];
                #pragma unroll
                for (int rr = 0; rr < 4; ++rr)
                    sT[(32 * wm + 16 * r + 4 * quad + rr) * 66 + col] = acc[r][c][rr] + bz;
            }
        soft_barrier();
        const int orow = t >> 2, ocb = (t & 3) * 16;
        f16 tmp[16];
        #pragma unroll
        for (int j = 0; j < 8; ++j) {
            float2 x = *(float2*)&sT[orow * 66 + ocb + 2 * j];
            tmp[2 * j] = (f16)x.x; tmp[2 * j + 1] = (f16)x.y;
        }
        f16* dst = ((mat == 0) ? qf : kf) + ((size_t)bh * NL + lbase + orow) * DH + ocb;
        *(f16x8*)dst       = *(f16x8*)&tmp[0];
        *(f16x8*)(dst + 8) = *(f16x8*)&tmp[8];
    } else {
        #pragma unroll
        for (int r = 0; r < 2; ++r)
            #pragma unroll
            for (int c = 0; c < 2; ++c) {
                const int col = 32 * wn + 16 * c + l15;
                const float bz = bias[h * 64 + col];
                #pragma unroll
                for (int rr = 0; rr < 4; ++rr)
                    sT[col * 66 + 32 * wm + 16 * r + 4 * quad + rr] = acc[r][c][rr] + bz;
            }
        soft_barrier();
        const int d = t >> 2, lcb = (t & 3) * 16;
        f16 tmp[16];
        #pragma unroll
        for (int j = 0; j < 8; ++j) {
            float2 x = *(float2*)&sT[d * 66 + lcb + 2 * j];
            tmp[2 * j] = (f16)x.x; tmp[2 * j + 1] = (f16)x.y;
        }
        f16* dst = vt + ((size_t)bh * DH + d) * NL + lbase + lcb;
        *(f16x8*)dst       = *(f16x8*)&tmp[0];
        *(f16x8*)(dst + 8) = *(f16x8*)&tmp[8];
    }
}

// ---------------------------------------------------------------------------
// Kernel B: qw[p,bh,l,e] = qf[bh,l,:] @ ssan_w[p,h]  via f16 MFMA (K=64).
// ---------------------------------------------------------------------------
__global__ __launch_bounds__(256, 4) void qw_kernel(
    const f16* __restrict__ qf, const f16* __restrict__ swt,
    f16* __restrict__ qwf)
{
    __shared__ f16 sA[64 * 72], sB[64 * 72];
    __shared__ float sT[64 * 66];

    const int l0 = blockIdx.x * 64;
    const int z  = blockIdx.y;      // 0..119
    const int p  = z / 24, bh = z % 24, h = bh % NH;
    const int t = threadIdx.x, lane = t & 63, w = t >> 6;
    const int quad = lane >> 4, l15 = lane & 15;
    const int wm = w >> 1, wn = w & 1;

    const int srow = t >> 2, scol = (t & 3) * 16;
    {
        const f16* As = qf + ((size_t)bh * NL + l0 + srow) * DH + scol;
        const f16* Bs = swt + ((size_t)(p * NH + h) * 64 + srow) * 64 + scol;
        *(f16x8*)&sA[srow * 72 + scol]     = *(const f16x8*)As;
        *(f16x8*)&sA[srow * 72 + scol + 8] = *(const f16x8*)(As + 8);
        *(f16x8*)&sB[srow * 72 + scol]     = *(const f16x8*)Bs;
        *(f16x8*)&sB[srow * 72 + scol + 8] = *(const f16x8*)(Bs + 8);
    }
    soft_barrier();

    f32x4 acc[2][2];
    #pragma unroll
    for (int r = 0; r < 2; ++r)
        #pragma unroll
        for (int c = 0; c < 2; ++c) acc[r][c] = (f32x4){0.f, 0.f, 0.f, 0.f};

    #pragma unroll
    for (int kk = 0; kk < 64; kk += 32) {
        const int ko = kk + quad * 8;
        f16x8 a0 = *(f16x8*)&sA[(32 * wm + l15) * 72 + ko];
        f16x8 a1 = *(f16x8*)&sA[(32 * wm + 16 + l15) * 72 + ko];
        f16x8 b0 = *(f16x8*)&sB[(32 * wn + l15) * 72 + ko];
        f16x8 b1 = *(f16x8*)&sB[(32 * wn + 16 + l15) * 72 + ko];
        acc[0][0] = MFMA16(a0, b0, acc[0][0]);
        acc[0][1] = MFMA16(a0, b1, acc[0][1]);
        acc[1][0] = MFMA16(a1, b0, acc[1][0]);
        acc[1][1] = MFMA16(a1, b1, acc[1][1]);
    }
    soft_barrier();

    #pragma unroll
    for (int r = 0; r < 2; ++r)
        #pragma unroll
        for (int c = 0; c < 2; ++c) {
            const int col = 32 * wn + 16 * c + l15;
            #pragma unroll
            for (int rr = 0; rr < 4; ++rr)
                sT[(32 * wm + 16 * r + 4 * quad + rr) * 66 + col] = acc[r][c][rr];
        }
    soft_barrier();

    const int orow = t >> 2, ocb = (t & 3) * 16;
    f16 tmp[16];
    #pragma unroll
    for (int j = 0; j < 8; ++j) {
        float2 x = *(float2*)&sT[orow * 66 + ocb + 2 * j];
        tmp[2 * j] = (f16)x.x; tmp[2 * j + 1] = (f16)x.y;
    }
    f16* dst = qwf + ((size_t)(p * 24 + bh) * NL + l0 + orow) * DH + ocb;
    *(f16x8*)dst       = *(f16x8*)&tmp[0];
    *(f16x8*)(dst + 8) = *(f16x8*)&tmp[8];
}

// ---------------------------------------------------------------------------
// Kernel P: posb[bh][l][r] = (q[bh,l] + k[bh,r]) . dist_emb[l-r+1023]   (f16)
// ---------------------------------------------------------------------------
__global__ __launch_bounds__(256, 2) void pos_kernel(
    const f16* __restrict__ qf, const f16* __restrict__ kf,
    const f16* __restrict__ de16, f16* __restrict__ posb)
{
    __shared__ f16 sQ[64 * 72], sK2[64 * 72];
    __shared__ f16 sE[128 * 72];
    __shared__ f16 sQE[64 * 140], sKE[64 * 140];

    const int l0 = blockIdx.x * 64;
    const int r0 = blockIdx.y * 64;
    const int bh = blockIdx.z;
    const int t  = threadIdx.x;
    const int lane = t & 63;
    const int w    = t >> 6;       // 0..3
    const int quad = lane >> 4;
    const int l15  = lane & 15;

    {
        const int row = t >> 3, col = (t & 7) * 8;
        const f16* qs = qf + ((size_t)bh * NL + l0) * DH;
        const f16* ks = kf + ((size_t)bh * NL + r0) * DH;
        *(f16x8*)&sQ[row * 72 + col]        = *(const f16x8*)&qs[row * 64 + col];
        *(f16x8*)&sQ[(row + 32) * 72 + col] = *(const f16x8*)&qs[(row + 32) * 64 + col];
        *(f16x8*)&sK2[row * 72 + col]        = *(const f16x8*)&ks[row * 64 + col];
        *(f16x8*)&sK2[(row + 32) * 72 + col] = *(const f16x8*)&ks[(row + 32) * 64 + col];
        const int ebase = l0 - r0 + 960;
        #pragma unroll
        for (int p = 0; p < 4; ++p) {
            const int er = row + 32 * p;
            if (er < 127)
                *(f16x8*)&sE[er * 72 + col] =
                    *(const f16x8*)&de16[(size_t)(ebase + er) * DH + col];
        }
    }
    soft_barrier();

    {
        const int arow = (16 * w + l15) * 72 + quad * 8;
        f16x8 aq0 = *(f16x8*)&sQ[arow];
        f16x8 aq1 = *(f16x8*)&sQ[arow + 32];
        f16x8 ak0 = *(f16x8*)&sK2[arow];
        f16x8 ak1 = *(f16x8*)&sK2[arow + 32];
        #pragma unroll
        for (int n = 0; n < 8; ++n) {
            const int brow = (16 * n + l15) * 72 + quad * 8;
            f16x8 e0 = *(f16x8*)&sE[brow];
            f16x8 e1 = *(f16x8*)&sE[brow + 32];
            f32x4 cq = {0.f, 0.f, 0.f, 0.f};
            cq = MFMA16(aq0, e0, cq);
            cq = MFMA16(aq1, e1, cq);
            f32x4 ck = {0.f, 0.f, 0.f, 0.f};
            ck = MFMA16(ak0, e0, ck);
            ck = MFMA16(ak1, e1, ck);
            #pragma unroll
            for (int r = 0; r < 4; ++r) {
                sQE[(16 * w + 4 * quad + r) * 140 + 16 * n + l15] = (f16)cq[r];
                sKE[(16 * w + 4 * quad + r) * 140 + 16 * n + l15] = (f16)ck[r];
            }
        }
    }
    soft_barrier();

    {
        const int i  = t >> 2;           // 0..63
        const int j0 = (t & 3) * 16;
        f16 res[16];
        #pragma unroll
        for (int jj = 0; jj < 16; ++jj) {
            const int j = j0 + jj;
            const int tt = i - j + 63;   // 0..126
            float v = (float)sQE[i * 140 + tt] + (float)sKE[j * 140 + tt];
            res[jj] = (f16)v;
        }
        f16* dst = posb + ((size_t)bh * NL + l0 + i) * NL + r0 + j0;
        *(f16x8*)dst       = *(f16x8*)&res[0];
        *(f16x8*)(dst + 8) = *(f16x8*)&res[8];
    }
}

// ---------------------------------------------------------------------------
// Kernel C: f16-MFMA flash attention.  Soft barriers keep global prefetch
// loads in flight across phase boundaries; VMEM issued before PV MFMAs.
// ---------------------------------------------------------------------------
__global__ __launch_bounds__(256, 2) void attn_kernel(
    const f16* __restrict__ qf, const f16* __restrict__ kf,
    const f16* __restrict__ vt, const f16* __restrict__ qwf,
    const float* __restrict__ mask, const float* __restrict__ struct_m,
    const f16* __restrict__ posb, const float* __restrict__ abs_bias,
    float* __restrict__ out)
{
    __shared__ f16 sK[64 * 72];
    __shared__ f16 sVt[2][64 * 72];
    __shared__ float sS[32 * 68];
    __shared__ f16 sP[32 * 72];
    __shared__ float sAlpha[32], sL[32];

    const int l0 = blockIdx.x * 32;
    const int bh = blockIdx.y;
    const int bb = bh / NH, h = bh % NH;
    const int t  = threadIdx.x;
    const int lane  = t & 63;
    const int w     = t >> 6;       // 0..3
    const int quad  = lane >> 4;
    const int l15   = lane & 15;
    const int msub  = w >> 1;       // 0..1
    const int npair = w & 1;        // 0..1

    const size_t NQKV = (size_t)NB * NH * NL * DH;

    f16x8 aQ[2], aW[5][2];
    {
        const size_t qrow = ((size_t)bh * NL + l0 + 16 * msub + l15) * DH;
        #pragma unroll
        for (int K = 0; K < 2; ++K) {
            aQ[K] = *(const f16x8*)&qf[qrow + 32 * K + 8 * quad];
            #pragma unroll
            for (int p = 0; p < 5; ++p)
                aW[p][K] = *(const f16x8*)&qwf[p * NQKV + qrow + 32 * K + 8 * quad];
        }
    }

    float ab[5];
    #pragma unroll
    for (int p = 0; p < 5; ++p) ab[p] = abs_bias[p * NH + h];

    float pf_st[5][2][4], pf_pos[2][4], pf_mask[2];

    auto stage_kv = [&](int r0s, int buf) {
        const int row = t >> 3, col = (t & 7) * 8;
        const f16* ks = kf + ((size_t)bh * NL + r0s) * DH;
        *(f16x8*)&sK[row * 72 + col]        = *(const f16x8*)&ks[row * 64 + col];
        *(f16x8*)&sK[(row + 32) * 72 + col] = *(const f16x8*)&ks[(row + 32) * 64 + col];
        const f16* vs = vt + (size_t)bh * DH * NL + r0s;
        *(f16x8*)&sVt[buf][row * 72 + col] =
            *(const f16x8*)&vs[(size_t)row * NL + col];
        *(f16x8*)&sVt[buf][(row + 32) * 72 + col] =
            *(const f16x8*)&vs[(size_t)(row + 32) * NL + col];
    };

    auto prefetch = [&](int r0s) {
        #pragma unroll
        for (int n = 0; n < 2; ++n) {
            const int j = 32 * npair + 16 * n + l15;
            pf_mask[n] = mask[bb * NL + r0s + j];
            #pragma unroll
            for (int r = 0; r < 4; ++r) {
                const int i = 16 * msub + 4 * quad + r;
                pf_pos[n][r] = (float)posb[((size_t)bh * NL + l0 + i) * NL + r0s + j];
                #pragma unroll
                for (int p = 0; p < 5; ++p)
                    pf_st[p][n][r] =
                        struct_m[((size_t)(p * NB + bb) * NL + l0 + i) * NL + r0s + j];
            }
        }
    };

    stage_kv(0, 0);
    prefetch(0);

    const int sm_i = t >> 3;
    const int sm_jb = t & 7;
    float m_cur = -INFINITY, l_cur = 0.f;
    f32x4 O[2];
    O[0] = (f32x4){0.f, 0.f, 0.f, 0.f};
    O[1] = (f32x4){0.f, 0.f, 0.f, 0.f};

    for (int kt = 0; kt < 16; ++kt) {
        const int cur = kt & 1;
        soft_barrier();                    // staging of this kt visible

        // ---- Phase C: score MFMAs + epilogue ----
        {
            f32x4 acc[2][6];
            #pragma unroll
            for (int n = 0; n < 2; ++n)
                #pragma unroll
                for (int p = 0; p < 6; ++p)
                    acc[n][p] = (f32x4){0.f, 0.f, 0.f, 0.f};

            #pragma unroll
            for (int K = 0; K < 2; ++K) {
                const int koff = K * 32 + quad * 8;
                f16x8 bk2[2];
                #pragma unroll
                for (int n = 0; n < 2; ++n)
                    bk2[n] = *(f16x8*)&sK[(32 * npair + 16 * n + l15) * 72 + koff];
                #pragma unroll
                for (int n = 0; n < 2; ++n)
                    acc[n][0] = MFMA16(aQ[K], bk2[n], acc[n][0]);
                #pragma unroll
                for (int p = 0; p < 5; ++p)
                    #pragma unroll
                    for (int n = 0; n < 2; ++n)
                        acc[n][1 + p] = MFMA16(aW[p][K], bk2[n], acc[n][1 + p]);
            }

            #pragma unroll
            for (int n = 0; n < 2; ++n) {
                const int j = 32 * npair + 16 * n + l15;
                #pragma unroll
                for (int r = 0; r < 4; ++r) {
                    const int i = 16 * msub + 4 * quad + r;
                    float s = (acc[n][0][r] + pf_pos[n][r]) * 0.125f + pf_mask[n];
                    #pragma unroll
                    for (int p = 0; p < 5; ++p)
                        s += (acc[n][1 + p][r] + ab[p]) * pf_st[p][n][r];
                    sS[i * 68 + j] = s;
                }
            }
        }
        soft_barrier();                    // sS published

        // ---- Phase D: online softmax ----
        {
            float sv[8];
            float smax = -INFINITY;
            #pragma unroll
            for (int k = 0; k < 8; ++k) {
                sv[k] = sS[sm_i * 68 + sm_jb + 8 * k];
                smax = fmaxf(smax, sv[k]);
            }
            #pragma unroll
            for (int off = 4; off > 0; off >>= 1)
                smax = fmaxf(smax, __shfl_xor(smax, off, 8));
            const float m_new = fmaxf(m_cur, smax);
            const float alpha = __expf(m_cur - m_new);
            float rsum = 0.f;
            #pragma unroll
            for (int k = 0; k < 8; ++k) {
                float p = __expf(sv[k] - m_new);
                sP[sm_i * 72 + sm_jb + 8 * k] = (f16)p;
                rsum += p;
            }
            #pragma unroll
            for (int off = 4; off > 0; off >>= 1)
                rsum += __shfl_xor(rsum, off, 8);
            l_cur = l_cur * alpha + rsum;
            m_cur = m_new;
            if (sm_jb == 0) { sAlpha[sm_i] = alpha; sL[sm_i] = l_cur; }
        }
        soft_barrier();                    // sP/alpha published

        // ---- Phase E: issue next-kt VMEM first, then PV MFMA ----
        {
            if (kt < 15) {
                stage_kv((kt + 1) * 64, cur ^ 1);
                prefetch((kt + 1) * 64);
            }

            float a4[4];
            #pragma unroll
            for (int r = 0; r < 4; ++r) a4[r] = sAlpha[16 * msub + 4 * quad + r];
            #pragma unroll
            for (int n = 0; n < 2; ++n)
                #pragma unroll
                for (int r = 0; r < 4; ++r) O[n][r] *= a4[r];

            const int prow = (16 * msub + l15) * 72;
            #pragma unroll
            for (int K = 0; K < 2; ++K) {
                const int koff = K * 32 + quad * 8;
                f16x8 pfr = *(f16x8*)&sP[prow + koff];
                #pragma unroll
                for (int n = 0; n < 2; ++n) {
                    f16x8 vfr = *(f16x8*)&sVt[cur][(32 * npair + 16 * n + l15) * 72 + koff];
                    O[n] = MFMA16(pfr, vfr, O[n]);
                }
            }
        }
    }

    float linv[4];
    #pragma unroll
    for (int r = 0; r < 4; ++r) linv[r] = 1.0f / sL[16 * msub + 4 * quad + r];
    #pragma unroll
    for (int n = 0; n < 2; ++n) {
        const int dh = 32 * npair + 16 * n + l15;
        #pragma unroll
        for (int r = 0; r < 4; ++r) {
            const int i = 16 * msub + 4 * quad + r;
            out[((size_t)bb * NL + l0 + i) * ND + h * DH + dh] = O[n][r] * linv[r];
        }
    }
}

// ---------------------------------------------------------------------------
extern "C" void kernel_launch(void* const* d_in, const int* in_sizes, int n_in,
                              void* d_out, int out_size, void* d_ws, size_t ws_size,
                              hipStream_t stream) {
    const float* hs   = (const float*)d_in[0];
    const float* mask = (const float*)d_in[1];
    const float* stm  = (const float*)d_in[2];
    const float* Wq   = (const float*)d_in[3];
    const float* bq   = (const float*)d_in[4];
    const float* Wk   = (const float*)d_in[5];
    const float* bk   = (const float*)d_in[6];
    const float* Wv   = (const float*)d_in[7];
    const float* bv   = (const float*)d_in[8];
    const float* de   = (const float*)d_in[9];
    const float* sw   = (const float*)d_in[10];
    const float* abb  = (const float*)d_in[11];
    float* outp = (float*)d_out;

    const size_t NQKV = (size_t)NB * NH * NL * DH;       // 1,572,864
    char* ws = (char*)d_ws;
    f16* qf   = (f16*)ws;                 ws += NQKV * 2;
    f16* kf   = (f16*)ws;                 ws += NQKV * 2;
    f16* vtb  = (f16*)ws;                 ws += NQKV * 2;
    f16* qwf  = (f16*)ws;                 ws += 5 * NQKV * 2;
    f16* posb = (f16*)ws;                 ws += (size_t)24 * 1024 * 1024 * 2;
    f16* de16 = (f16*)ws;                 // 2047*64 f16 = 262 KB
    // hsf/wt/swt overlay the posb region: dead before pos_kernel overwrites.
    f16* hsf = posb;
    f16* wt  = hsf + NQKV;
    f16* swt = wt + (size_t)2304 * 768;

    prep_kernel<<<1324, 256, 0, stream>>>(hs, Wq, Wk, Wv, sw, de,
                                          hsf, wt, swt, de16);
    qkv_kernel<<<dim3(32, 36), 256, 0, stream>>>(hsf, wt, bq, bk, bv, qf, kf, vtb);
    qw_kernel<<<dim3(16, 120), 256, 0, stream>>>(qf, swt, qwf);
    pos_kernel<<<dim3(16, 16, 24), 256, 0, stream>>>(qf, kf, de16, posb);
    attn_kernel<<<dim3(32, 24), 256, 0, stream>>>(qf, kf, vtb, qwf,
                                                  mask, stm, posb, abb, outp);
}

// Round 6
// 243.152 us; speedup vs baseline: 4.0665x; 1.0116x over previous
//
#include <hip/hip_runtime.h>
#include <math.h>

#define NB 2
#define NL 1024
#define ND 768
#define NH 12
#define DH 64

typedef _Float16 f16;
typedef _Float16 f16x4 __attribute__((ext_vector_type(4)));
typedef _Float16 f16x8 __attribute__((ext_vector_type(8)));
typedef float f32x4 __attribute__((ext_vector_type(4)));

#define MFMA16(a, b, c) __builtin_amdgcn_mfma_f32_16x16x32_f16((a), (b), (c), 0, 0, 0)

// LDS-only barrier (does not force vmcnt drain).
__device__ __forceinline__ void soft_barrier() {
    asm volatile("s_waitcnt lgkmcnt(0)\n\ts_barrier" ::: "memory");
}

// ---------------------------------------------------------------------------
// Kernel 0: prep.
//   tiles 0..767    : hs fp32 -> hsf f16
//   tiles 768..1199 : W{q,k,v} -> wt f16 [(mat*12+h)*64+n][k]   (transposed)
//   tiles 1200..1259: ssan_w -> swt f16 [p][h][e][d]            (transposed)
//   tiles 1260..1323: dist_emb fp32 -> de16 f16
// ---------------------------------------------------------------------------
__global__ __launch_bounds__(256) void prep_kernel(
    const float* __restrict__ hs,
    const float* __restrict__ Wq, const float* __restrict__ Wk,
    const float* __restrict__ Wv, const float* __restrict__ sw,
    const float* __restrict__ de,
    f16* __restrict__ hsf, f16* __restrict__ wt, f16* __restrict__ swt,
    f16* __restrict__ de16)
{
    __shared__ float sT[64 * 66];
    const int t = threadIdx.x;
    const int tile = blockIdx.x;

    if (tile < 768) {
        const int base = tile * 2048 + t * 8;
        float4 a = *(const float4*)&hs[base];
        float4 b = *(const float4*)&hs[base + 4];
        f16x8 hv;
        hv[0] = (f16)a.x; hv[1] = (f16)a.y; hv[2] = (f16)a.z; hv[3] = (f16)a.w;
        hv[4] = (f16)b.x; hv[5] = (f16)b.y; hv[6] = (f16)b.z; hv[7] = (f16)b.w;
        *(f16x8*)&hsf[base] = hv;
        return;
    }
    if (tile >= 1260) {
        const int base = (tile - 1260) * 2048 + t * 8;
        if (base < 2047 * 64) {
            float4 a = *(const float4*)&de[base];
            float4 b = *(const float4*)&de[base + 4];
            f16x8 hv;
            hv[0] = (f16)a.x; hv[1] = (f16)a.y; hv[2] = (f16)a.z; hv[3] = (f16)a.w;
            hv[4] = (f16)b.x; hv[5] = (f16)b.y; hv[6] = (f16)b.z; hv[7] = (f16)b.w;
            *(f16x8*)&de16[base] = hv;
        }
        return;
    }

    const float* S; f16* D; int sRS, dRS;
    const int ti = tile - 768;
    if (ti < 432) {
        const int mat = ti / 144, r2 = ti % 144, ht = r2 / 12, kt = r2 % 12;
        const float* W = (mat == 0) ? Wq : (mat == 1) ? Wk : Wv;
        S = W + (size_t)(kt * 64) * ND + ht * 64;
        D = wt + (size_t)((mat * NH + ht) * 64) * ND + kt * 64;
        sRS = ND; dRS = ND;
    } else {
        const int i = ti - 432;
        S = sw + (size_t)i * 4096;
        D = swt + (size_t)i * 4096;
        sRS = 64; dRS = 64;
    }

    {
        const int kk = t >> 2, nb = (t & 3) * 16;
        float v[16];
        #pragma unroll
        for (int j = 0; j < 4; ++j)
            *(float4*)&v[4 * j] = *(const float4*)&S[(size_t)kk * sRS + nb + 4 * j];
        #pragma unroll
        for (int jj = 0; jj < 16; ++jj)
            sT[(nb + jj) * 66 + kk] = v[jj];
    }
    soft_barrier();
    {
        const int n = t >> 2, kb = (t & 3) * 16;
        f16 tmp[16];
        #pragma unroll
        for (int j = 0; j < 8; ++j) {
            float2 x = *(float2*)&sT[n * 66 + kb + 2 * j];
            tmp[2 * j]     = (f16)x.x;
            tmp[2 * j + 1] = (f16)x.y;
        }
        *(f16x8*)&D[(size_t)n * dRS + kb]     = *(f16x8*)&tmp[0];
        *(f16x8*)&D[(size_t)n * dRS + kb + 8] = *(f16x8*)&tmp[8];
    }
}

// ---------------------------------------------------------------------------
// Kernel A: QKV projection, f16 MFMA.  64x64 tile, 4 waves, 2x2 subtiles/wave.
// ---------------------------------------------------------------------------
__global__ __launch_bounds__(256, 4) void qkv_kernel(
    const f16* __restrict__ hsf, const f16* __restrict__ wt,
    const float* __restrict__ bq, const float* __restrict__ bk,
    const float* __restrict__ bv,
    f16* __restrict__ qf, f16* __restrict__ kf, f16* __restrict__ vt)
{
    __shared__ f16 sA[64 * 72], sB[64 * 72];
    __shared__ float sT[64 * 66];

    const int m0  = blockIdx.x * 64;
    const int y   = blockIdx.y;          // 0..35
    const int mat = y / NH, h = y % NH;
    const int t = threadIdx.x, lane = t & 63, w = t >> 6;
    const int quad = lane >> 4, l15 = lane & 15;
    const int wm = w >> 1, wn = w & 1;

    const float* bias = (mat == 0) ? bq : (mat == 1) ? bk : bv;

    f32x4 acc[2][2];
    #pragma unroll
    for (int r = 0; r < 2; ++r)
        #pragma unroll
        for (int c = 0; c < 2; ++c) acc[r][c] = (f32x4){0.f, 0.f, 0.f, 0.f};

    const int srow = t >> 2, scol = (t & 3) * 16;
    const f16* Ag = hsf + (size_t)(m0 + srow) * ND + scol;
    const f16* Bg = wt + ((size_t)y * 64 + srow) * ND + scol;

    for (int k0 = 0; k0 < ND; k0 += 64) {
        soft_barrier();
        *(f16x8*)&sA[srow * 72 + scol]     = *(const f16x8*)&Ag[k0];
        *(f16x8*)&sA[srow * 72 + scol + 8] = *(const f16x8*)&Ag[k0 + 8];
        *(f16x8*)&sB[srow * 72 + scol]     = *(const f16x8*)&Bg[k0];
        *(f16x8*)&sB[srow * 72 + scol + 8] = *(const f16x8*)&Bg[k0 + 8];
        soft_barrier();
        #pragma unroll
        for (int kk = 0; kk < 64; kk += 32) {
            const int ko = kk + quad * 8;
            f16x8 a0 = *(f16x8*)&sA[(32 * wm + l15) * 72 + ko];
            f16x8 a1 = *(f16x8*)&sA[(32 * wm + 16 + l15) * 72 + ko];
            f16x8 b0 = *(f16x8*)&sB[(32 * wn + l15) * 72 + ko];
            f16x8 b1 = *(f16x8*)&sB[(32 * wn + 16 + l15) * 72 + ko];
            acc[0][0] = MFMA16(a0, b0, acc[0][0]);
            acc[0][1] = MFMA16(a0, b1, acc[0][1]);
            acc[1][0] = MFMA16(a1, b0, acc[1][0]);
            acc[1][1] = MFMA16(a1, b1, acc[1][1]);
        }
    }
    soft_barrier();

    const int bb = m0 >> 10;
    const int lbase = m0 & 1023;
    const int bh = bb * NH + h;

    if (mat < 2) {
        #pragma unroll
        for (int r = 0; r < 2; ++r)
            #pragma unroll
            for (int c = 0; c < 2; ++c) {
                const int col = 32 * wn + 16 * c + l15;
                const float bz = bias[h * 64 + col];
                #pragma unroll
                for (int rr = 0; rr < 4; ++rr)
                    sT[(32 * wm + 16 * r + 4 * quad + rr) * 66 + col] = acc[r][c][rr] + bz;
            }
        soft_barrier();
        const int orow = t >> 2, ocb = (t & 3) * 16;
        f16 tmp[16];
        #pragma unroll
        for (int j = 0; j < 8; ++j) {
            float2 x = *(float2*)&sT[orow * 66 + ocb + 2 * j];
            tmp[2 * j] = (f16)x.x; tmp[2 * j + 1] = (f16)x.y;
        }
        f16* dst = ((mat == 0) ? qf : kf) + ((size_t)bh * NL + lbase + orow) * DH + ocb;
        *(f16x8*)dst       = *(f16x8*)&tmp[0];
        *(f16x8*)(dst + 8) = *(f16x8*)&tmp[8];
    } else {
        #pragma unroll
        for (int r = 0; r < 2; ++r)
            #pragma unroll
            for (int c = 0; c < 2; ++c) {
                const int col = 32 * wn + 16 * c + l15;
                const float bz = bias[h * 64 + col];
                #pragma unroll
                for (int rr = 0; rr < 4; ++rr)
                    sT[col * 66 + 32 * wm + 16 * r + 4 * quad + rr] = acc[r][c][rr] + bz;
            }
        soft_barrier();
        const int d = t >> 2, lcb = (t & 3) * 16;
        f16 tmp[16];
        #pragma unroll
        for (int j = 0; j < 8; ++j) {
            float2 x = *(float2*)&sT[d * 66 + lcb + 2 * j];
            tmp[2 * j] = (f16)x.x; tmp[2 * j + 1] = (f16)x.y;
        }
        f16* dst = vt + ((size_t)bh * DH + d) * NL + lbase + lcb;
        *(f16x8*)dst       = *(f16x8*)&tmp[0];
        *(f16x8*)(dst + 8) = *(f16x8*)&tmp[8];
    }
}

// ---------------------------------------------------------------------------
// Kernel B: qw[p,bh,l,e] = qf[bh,l,:] @ ssan_w[p,h]  via f16 MFMA (K=64).
// ---------------------------------------------------------------------------
__global__ __launch_bounds__(256, 4) void qw_kernel(
    const f16* __restrict__ qf, const f16* __restrict__ swt,
    f16* __restrict__ qwf)
{
    __shared__ f16 sA[64 * 72], sB[64 * 72];
    __shared__ float sT[64 * 66];

    const int l0 = blockIdx.x * 64;
    const int z  = blockIdx.y;      // 0..119
    const int p  = z / 24, bh = z % 24, h = bh % NH;
    const int t = threadIdx.x, lane = t & 63, w = t >> 6;
    const int quad = lane >> 4, l15 = lane & 15;
    const int wm = w >> 1, wn = w & 1;

    const int srow = t >> 2, scol = (t & 3) * 16;
    {
        const f16* As = qf + ((size_t)bh * NL + l0 + srow) * DH + scol;
        const f16* Bs = swt + ((size_t)(p * NH + h) * 64 + srow) * 64 + scol;
        *(f16x8*)&sA[srow * 72 + scol]     = *(const f16x8*)As;
        *(f16x8*)&sA[srow * 72 + scol + 8] = *(const f16x8*)(As + 8);
        *(f16x8*)&sB[srow * 72 + scol]     = *(const f16x8*)Bs;
        *(f16x8*)&sB[srow * 72 + scol + 8] = *(const f16x8*)(Bs + 8);
    }
    soft_barrier();

    f32x4 acc[2][2];
    #pragma unroll
    for (int r = 0; r < 2; ++r)
        #pragma unroll
        for (int c = 0; c < 2; ++c) acc[r][c] = (f32x4){0.f, 0.f, 0.f, 0.f};

    #pragma unroll
    for (int kk = 0; kk < 64; kk += 32) {
        const int ko = kk + quad * 8;
        f16x8 a0 = *(f16x8*)&sA[(32 * wm + l15) * 72 + ko];
        f16x8 a1 = *(f16x8*)&sA[(32 * wm + 16 + l15) * 72 + ko];
        f16x8 b0 = *(f16x8*)&sB[(32 * wn + l15) * 72 + ko];
        f16x8 b1 = *(f16x8*)&sB[(32 * wn + 16 + l15) * 72 + ko];
        acc[0][0] = MFMA16(a0, b0, acc[0][0]);
        acc[0][1] = MFMA16(a0, b1, acc[0][1]);
        acc[1][0] = MFMA16(a1, b0, acc[1][0]);
        acc[1][1] = MFMA16(a1, b1, acc[1][1]);
    }
    soft_barrier();

    #pragma unroll
    for (int r = 0; r < 2; ++r)
        #pragma unroll
        for (int c = 0; c < 2; ++c) {
            const int col = 32 * wn + 16 * c + l15;
            #pragma unroll
            for (int rr = 0; rr < 4; ++rr)
                sT[(32 * wm + 16 * r + 4 * quad + rr) * 66 + col] = acc[r][c][rr];
        }
    soft_barrier();

    const int orow = t >> 2, ocb = (t & 3) * 16;
    f16 tmp[16];
    #pragma unroll
    for (int j = 0; j < 8; ++j) {
        float2 x = *(float2*)&sT[orow * 66 + ocb + 2 * j];
        tmp[2 * j] = (f16)x.x; tmp[2 * j + 1] = (f16)x.y;
    }
    f16* dst = qwf + ((size_t)(p * 24 + bh) * NL + l0 + orow) * DH + ocb;
    *(f16x8*)dst       = *(f16x8*)&tmp[0];
    *(f16x8*)(dst + 8) = *(f16x8*)&tmp[8];
}

// ---------------------------------------------------------------------------
// Kernel C: f16-MFMA flash attention with FUSED positional band-GEMMs.
// 256 threads (4 waves), q-tile 32, k-tile 64.  Per kt:
//   Phase B: QE = Q@Eband^T (wave's resident aQ is the A-frag: mi==msub),
//            KE = K@Eband^T (A from sK).  C-tiles stored TRANSPOSED:
//            sQEl[t'][i] pitch 34 (17-bank lane stride, conflict-free),
//            sKEl[t'][j] pitch 66 (33-bank stride, conflict-free).
//   Phase C: 24 score MFMAs + epilogue gathers pos via t' = i-j+63.
// ---------------------------------------------------------------------------
__global__ __launch_bounds__(256, 2) void attn_kernel(
    const f16* __restrict__ qf, const f16* __restrict__ kf,
    const f16* __restrict__ vt, const f16* __restrict__ qwf,
    const float* __restrict__ mask, const float* __restrict__ struct_m,
    const f16* __restrict__ de16, const float* __restrict__ abs_bias,
    float* __restrict__ out)
{
    __shared__ f16 sK[64 * 72];
    __shared__ f16 sVt[2][64 * 72];
    __shared__ f16 sE[96 * 72];      // E band rows 0..94 (t' = i-j+63)
    __shared__ f16 sQEl[96 * 34];    // [t'][i]
    __shared__ f16 sKEl[96 * 66];    // [t'][j]
    __shared__ float sS[32 * 68];
    __shared__ f16 sP[32 * 72];
    __shared__ float sAlpha[32], sL[32];

    const int l0 = blockIdx.x * 32;
    const int bh = blockIdx.y;
    const int bb = bh / NH, h = bh % NH;
    const int t  = threadIdx.x;
    const int lane  = t & 63;
    const int w     = t >> 6;       // 0..3
    const int quad  = lane >> 4;
    const int l15   = lane & 15;
    const int msub  = w >> 1;       // 0..1
    const int npair = w & 1;        // 0..1

    const size_t NQKV = (size_t)NB * NH * NL * DH;

    f16x8 aQ[2], aW[5][2];
    {
        const size_t qrow = ((size_t)bh * NL + l0 + 16 * msub + l15) * DH;
        #pragma unroll
        for (int K = 0; K < 2; ++K) {
            aQ[K] = *(const f16x8*)&qf[qrow + 32 * K + 8 * quad];
            #pragma unroll
            for (int p = 0; p < 5; ++p)
                aW[p][K] = *(const f16x8*)&qwf[p * NQKV + qrow + 32 * K + 8 * quad];
        }
    }

    float ab[5];
    #pragma unroll
    for (int p = 0; p < 5; ++p) ab[p] = abs_bias[p * NH + h];

    float pf_st[5][2][4], pf_mask[2];

    auto stage_kv = [&](int r0s, int buf) {
        const int row = t >> 3, col = (t & 7) * 8;
        const f16* ks = kf + ((size_t)bh * NL + r0s) * DH;
        *(f16x8*)&sK[row * 72 + col]        = *(const f16x8*)&ks[row * 64 + col];
        *(f16x8*)&sK[(row + 32) * 72 + col] = *(const f16x8*)&ks[(row + 32) * 64 + col];
        const f16* vs = vt + (size_t)bh * DH * NL + r0s;
        *(f16x8*)&sVt[buf][row * 72 + col] =
            *(const f16x8*)&vs[(size_t)row * NL + col];
        *(f16x8*)&sVt[buf][(row + 32) * 72 + col] =
            *(const f16x8*)&vs[(size_t)(row + 32) * NL + col];
    };

    auto stage_E = [&](int r0s) {
        const int ebase = l0 - r0s + 960;
        #pragma unroll
        for (int p = 0; p < 3; ++p) {
            const int idx = t + 256 * p;
            const int er = idx >> 3, col = (idx & 7) * 8;
            if (er < 95)
                *(f16x8*)&sE[er * 72 + col] =
                    *(const f16x8*)&de16[(size_t)(ebase + er) * DH + col];
        }
    };

    auto prefetch = [&](int r0s) {
        #pragma unroll
        for (int n = 0; n < 2; ++n) {
            const int j = 32 * npair + 16 * n + l15;
            pf_mask[n] = mask[bb * NL + r0s + j];
            #pragma unroll
            for (int r = 0; r < 4; ++r) {
                const int i = 16 * msub + 4 * quad + r;
                #pragma unroll
                for (int p = 0; p < 5; ++p)
                    pf_st[p][n][r] =
                        struct_m[((size_t)(p * NB + bb) * NL + l0 + i) * NL + r0s + j];
            }
        }
    };

    stage_kv(0, 0);
    stage_E(0);
    prefetch(0);

    const int sm_i = t >> 3;
    const int sm_jb = t & 7;
    float m_cur = -INFINITY, l_cur = 0.f;
    f32x4 O[2];
    O[0] = (f32x4){0.f, 0.f, 0.f, 0.f};
    O[1] = (f32x4){0.f, 0.f, 0.f, 0.f};

    for (int kt = 0; kt < 16; ++kt) {
        const int cur = kt & 1;
        soft_barrier();                    // staging of this kt visible

        // ---- Phase B: positional band GEMMs ----
        {
            f16x8 ak0 = *(f16x8*)&sK[(16 * w + l15) * 72 + quad * 8];
            f16x8 ak1 = *(f16x8*)&sK[(16 * w + l15) * 72 + 32 + quad * 8];
            // QE: wave covers mi = msub, nt = 3*npair + c
            #pragma unroll
            for (int c = 0; c < 3; ++c) {
                const int nt = 3 * npair + c;
                f16x8 e0 = *(f16x8*)&sE[(16 * nt + l15) * 72 + quad * 8];
                f16x8 e1 = *(f16x8*)&sE[(16 * nt + l15) * 72 + 32 + quad * 8];
                f32x4 cq = {0.f, 0.f, 0.f, 0.f};
                cq = MFMA16(aQ[0], e0, cq);
                cq = MFMA16(aQ[1], e1, cq);
                #pragma unroll
                for (int r = 0; r < 4; ++r)
                    sQEl[(16 * nt + l15) * 34 + 16 * msub + 4 * quad + r] = (f16)cq[r];
            }
            // KE: wave covers j-tile w, all 6 nt
            #pragma unroll
            for (int nt = 0; nt < 6; ++nt) {
                f16x8 e0 = *(f16x8*)&sE[(16 * nt + l15) * 72 + quad * 8];
                f16x8 e1 = *(f16x8*)&sE[(16 * nt + l15) * 72 + 32 + quad * 8];
                f32x4 ck = {0.f, 0.f, 0.f, 0.f};
                ck = MFMA16(ak0, e0, ck);
                ck = MFMA16(ak1, e1, ck);
                #pragma unroll
                for (int r = 0; r < 4; ++r)
                    sKEl[(16 * nt + l15) * 66 + 16 * w + 4 * quad + r] = (f16)ck[r];
            }
        }
        soft_barrier();                    // sQEl/sKEl published

        // ---- Phase C: score MFMAs + epilogue (with pos gather) ----
        {
            f32x4 acc[2][6];
            #pragma unroll
            for (int n = 0; n < 2; ++n)
                #pragma unroll
                for (int p = 0; p < 6; ++p)
                    acc[n][p] = (f32x4){0.f, 0.f, 0.f, 0.f};

            #pragma unroll
            for (int K = 0; K < 2; ++K) {
                const int koff = K * 32 + quad * 8;
                f16x8 bk2[2];
                #pragma unroll
                for (int n = 0; n < 2; ++n)
                    bk2[n] = *(f16x8*)&sK[(32 * npair + 16 * n + l15) * 72 + koff];
                #pragma unroll
                for (int n = 0; n < 2; ++n)
                    acc[n][0] = MFMA16(aQ[K], bk2[n], acc[n][0]);
                #pragma unroll
                for (int p = 0; p < 5; ++p)
                    #pragma unroll
                    for (int n = 0; n < 2; ++n)
                        acc[n][1 + p] = MFMA16(aW[p][K], bk2[n], acc[n][1 + p]);
            }

            #pragma unroll
            for (int n = 0; n < 2; ++n) {
                const int j = 32 * npair + 16 * n + l15;
                #pragma unroll
                for (int r = 0; r < 4; ++r) {
                    const int i = 16 * msub + 4 * quad + r;
                    const int tp = i - j + 63;
                    float posv = (float)sQEl[tp * 34 + i] + (float)sKEl[tp * 66 + j];
                    float s = (acc[n][0][r] + posv) * 0.125f + pf_mask[n];
                    #pragma unroll
                    for (int p = 0; p < 5; ++p)
                        s += (acc[n][1 + p][r] + ab[p]) * pf_st[p][n][r];
                    sS[i * 68 + j] = s;
                }
            }
        }
        soft_barrier();                    // sS published

        // ---- Phase D: online softmax ----
        {
            float sv[8];
            float smax = -INFINITY;
            #pragma unroll
            for (int k = 0; k < 8; ++k) {
                sv[k] = sS[sm_i * 68 + sm_jb + 8 * k];
                smax = fmaxf(smax, sv[k]);
            }
            #pragma unroll
            for (int off = 4; off > 0; off >>= 1)
                smax = fmaxf(smax, __shfl_xor(smax, off, 8));
            const float m_new = fmaxf(m_cur, smax);
            const float alpha = __expf(m_cur - m_new);
            float rsum = 0.f;
            #pragma unroll
            for (int k = 0; k < 8; ++k) {
                float p = __expf(sv[k] - m_new);
                sP[sm_i * 72 + sm_jb + 8 * k] = (f16)p;
                rsum += p;
            }
            #pragma unroll
            for (int off = 4; off > 0; off >>= 1)
                rsum += __shfl_xor(rsum, off, 8);
            l_cur = l_cur * alpha + rsum;
            m_cur = m_new;
            if (sm_jb == 0) { sAlpha[sm_i] = alpha; sL[sm_i] = l_cur; }
        }
        soft_barrier();                    // sP/alpha published

        // ---- Phase E: issue next-kt VMEM, then PV MFMA ----
        {
            if (kt < 15) {
                stage_kv((kt + 1) * 64, cur ^ 1);
                stage_E((kt + 1) * 64);
                prefetch((kt + 1) * 64);
            }

            float a4[4];
            #pragma unroll
            for (int r = 0; r < 4; ++r) a4[r] = sAlpha[16 * msub + 4 * quad + r];
            #pragma unroll
            for (int n = 0; n < 2; ++n)
                #pragma unroll
                for (int r = 0; r < 4; ++r) O[n][r] *= a4[r];

            const int prow = (16 * msub + l15) * 72;
            #pragma unroll
            for (int K = 0; K < 2; ++K) {
                const int koff = K * 32 + quad * 8;
                f16x8 pfr = *(f16x8*)&sP[prow + koff];
                #pragma unroll
                for (int n = 0; n < 2; ++n) {
                    f16x8 vfr = *(f16x8*)&sVt[cur][(32 * npair + 16 * n + l15) * 72 + koff];
                    O[n] = MFMA16(pfr, vfr, O[n]);
                }
            }
        }
    }

    float linv[4];
    #pragma unroll
    for (int r = 0; r < 4; ++r) linv[r] = 1.0f / sL[16 * msub + 4 * quad + r];
    #pragma unroll
    for (int n = 0; n < 2; ++n) {
        const int dh = 32 * npair + 16 * n + l15;
        #pragma unroll
        for (int r = 0; r < 4; ++r) {
            const int i = 16 * msub + 4 * quad + r;
            out[((size_t)bb * NL + l0 + i) * ND + h * DH + dh] = O[n][r] * linv[r];
        }
    }
}

// ---------------------------------------------------------------------------
extern "C" void kernel_launch(void* const* d_in, const int* in_sizes, int n_in,
                              void* d_out, int out_size, void* d_ws, size_t ws_size,
                              hipStream_t stream) {
    const float* hs   = (const float*)d_in[0];
    const float* mask = (const float*)d_in[1];
    const float* stm  = (const float*)d_in[2];
    const float* Wq   = (const float*)d_in[3];
    const float* bq   = (const float*)d_in[4];
    const float* Wk   = (const float*)d_in[5];
    const float* bk   = (const float*)d_in[6];
    const float* Wv   = (const float*)d_in[7];
    const float* bv   = (const float*)d_in[8];
    const float* de   = (const float*)d_in[9];
    const float* sw   = (const float*)d_in[10];
    const float* abb  = (const float*)d_in[11];
    float* outp = (float*)d_out;

    const size_t NQKV = (size_t)NB * NH * NL * DH;       // 1,572,864
    char* ws = (char*)d_ws;
    f16* qf   = (f16*)ws;                 ws += NQKV * 2;
    f16* kf   = (f16*)ws;                 ws += NQKV * 2;
    f16* vtb  = (f16*)ws;                 ws += NQKV * 2;
    f16* qwf  = (f16*)ws;                 ws += 5 * NQKV * 2;
    f16* hsf  = (f16*)ws;                 ws += NQKV * 2;
    f16* wt   = (f16*)ws;                 ws += (size_t)2304 * 768 * 2;
    f16* swt  = (f16*)ws;                 ws += (size_t)245760 * 2;
    f16* de16 = (f16*)ws;                 // 2047*64 f16 = 262 KB

    prep_kernel<<<1324, 256, 0, stream>>>(hs, Wq, Wk, Wv, sw, de,
                                          hsf, wt, swt, de16);
    qkv_kernel<<<dim3(32, 36), 256, 0, stream>>>(hsf, wt, bq, bk, bv, qf, kf, vtb);
    qw_kernel<<<dim3(16, 120), 256, 0, stream>>>(qf, swt, qwf);
    attn_kernel<<<dim3(32, 24), 256, 0, stream>>>(qf, kf, vtb, qwf,
                                                  mask, stm, de16, abb, outp);
}